// Round 5
// baseline (1124.927 us; speedup 1.0000x reference)
//
#include <hip/hip_runtime.h>

#define B_ 256
#define C_ 64
#define L_ 512
#define CIN_ 82
#define NFREQ_ 9
#define EMB_ 256
#define NLAB_ 10
#define PT_ 37056
#define OFF_BH 16384
#define OFF_WL 16448
#define OFF_BL 20544
#define OFF_WS 20608
#define OFF_BS 36992
#define PI_F 3.14159265358979323846f

typedef short bh8 __attribute__((ext_vector_type(8)));   // 8 bf16 (raw bits)
typedef float f32x4 __attribute__((ext_vector_type(4)));
typedef float f32x8 __attribute__((ext_vector_type(8)));

__device__ inline float lrelu(float v){ return v > 0.f ? v : 0.2f*v; }

__device__ inline unsigned short f2bf(float f){
  unsigned u = __float_as_uint(f);
  u += 0x7FFFu + ((u >> 16) & 1u);      // RNE
  return (unsigned short)(u >> 16);
}
__device__ inline float bf2f(unsigned short u){
  return __uint_as_float((unsigned)u << 16);
}
__device__ inline unsigned pk2(float a, float b){
  return (unsigned)f2bf(a) | ((unsigned)f2bf(b) << 16);
}
__device__ inline bh8 cvt8(float4 a, float4 b){
  bh8 r;
  r[0]=(short)f2bf(a.x); r[1]=(short)f2bf(a.y); r[2]=(short)f2bf(a.z); r[3]=(short)f2bf(a.w);
  r[4]=(short)f2bf(b.x); r[5]=(short)f2bf(b.y); r[6]=(short)f2bf(b.z); r[7]=(short)f2bf(b.w);
  return r;
}
__device__ inline uint4 pk8(const float* v){
  uint4 o = { pk2(v[0],v[1]), pk2(v[2],v[3]), pk2(v[4],v[5]), pk2(v[6],v[7]) };
  return o;
}
// in-wave lane fetch via LDS-pipe permute (addr = src_lane*4)
__device__ inline float shf(float v, int a){
  return __uint_as_float((unsigned)__builtin_amdgcn_ds_bpermute(a, (int)__float_as_uint(v)));
}

// ---------------- yemb: normalize(fc_w[:,y]+fc_b) -> bf16 [b][e]; zero loss slot
__global__ __launch_bounds__(256) void k_yemb(const float* __restrict__ fc_w,
    const float* __restrict__ fc_b, const int* __restrict__ y,
    unsigned short* __restrict__ ybf, float* __restrict__ out){
  int b = blockIdx.x, e = threadIdx.x;
  int lab = y[b];
  float v = fc_w[e*NLAB_ + lab] + fc_b[e];
  __shared__ float red[256];
  red[e] = v*v; __syncthreads();
  for (int s = 128; s; s >>= 1){ if (e < s) red[e] += red[e+s]; __syncthreads(); }
  float nrm = fmaxf(sqrtf(red[0]), 1e-12f);
  ybf[(size_t)b*EMB_ + e] = f2bf(v / nrm);
  if (b == 0 && e == 0) out[B_*L_] = 0.f;
}

// ---------------- hyper (MFMA): p_bf[b][j] = bf16(yemb[b][:] . hw[j][:] + hb[j])
__global__ __launch_bounds__(256) void k_hyper(const float* __restrict__ hw,
    const float* __restrict__ hb, const unsigned short* __restrict__ ybf,
    unsigned short* __restrict__ p_bf){
  int tid = threadIdx.x;
  int wid = tid >> 6, lane = tid & 63, col = lane & 15, quad = lane >> 4;
  int j = blockIdx.x*64 + wid*16 + col;
  f32x4 acc[16];
  f32x4 z4 = {0.f,0.f,0.f,0.f};
  #pragma unroll
  for (int i = 0; i < 16; i++) acc[i] = z4;
  for (int k0 = 0; k0 < 256; k0 += 32){
    const float* hp = hw + (size_t)j*EMB_ + k0 + quad*8;
    bh8 bf = cvt8(*(const float4*)hp, *(const float4*)(hp+4));
    #pragma unroll
    for (int mt = 0; mt < 16; mt++){
      bh8 af = *(const bh8*)&ybf[(size_t)(mt*16 + col)*EMB_ + k0 + quad*8];
      acc[mt] = __builtin_amdgcn_mfma_f32_16x16x32_bf16(af, bf, acc[mt], 0, 0, 0);
    }
  }
  float hbv = hb[j];
  #pragma unroll
  for (int mt = 0; mt < 16; mt++){
    int b0 = mt*16 + quad*4;
    #pragma unroll
    for (int r = 0; r < 4; r++)
      p_bf[(size_t)(b0 + r)*PT_ + j] = f2bf(acc[mt][r] + hbv);
  }
}

// positional encoding value (raw)
__device__ inline float pe_raw(int fi, int l){
  if (fi < NFREQ_) return __sinf(PI_F / (float)(1 << fi) * (float)l);
  return __cosf(PI_F / (float)(1 << (fi - NFREQ_)) * (float)l);
}

// ---------------- conv_in1 (MFMA): t1bf[b][l][m] = bf16(lrelu(conv3(leaky(xcat), in_w0)+in_b0))
__global__ __launch_bounds__(256) void k_conv_in1(const float* __restrict__ codes,
    const float* __restrict__ w0, const float* __restrict__ b0,
    unsigned short* __restrict__ t1bf){
  int b = blockIdx.x, l0 = blockIdx.y*128, tid = threadIdx.x;
  int wid = tid>>6, lane = tid&63, col = lane&15, quad = lane>>4;
  __shared__ __attribute__((aligned(16))) unsigned short xT[136][96];
  __shared__ __attribute__((aligned(16))) unsigned short wA[3][64][96];
  for (int i = tid; i < 64*96; i += 256){
    int m = i / 96, cin = i % 96;
    if (cin < CIN_){
      const float* s = w0 + (size_t)m*(CIN_*3) + cin*3;
      wA[0][m][cin] = f2bf(s[0]); wA[1][m][cin] = f2bf(s[1]); wA[2][m][cin] = f2bf(s[2]);
    } else { wA[0][m][cin] = 0; wA[1][m][cin] = 0; wA[2][m][cin] = 0; }
  }
  const float* cb = codes + (size_t)b*C_*L_;
  for (int i = tid; i < 96*34; i += 256){
    int c = i / 34, g = i % 34;
    int lg = l0 - 4 + 4*g;
    #pragma unroll
    for (int r2 = 0; r2 < 4; r2++){
      int l = lg + r2;
      float xv = 0.f;
      if (l >= 0 && l < L_){
        if (c < C_) xv = cb[(size_t)c*L_ + l];
        else if (c < CIN_) xv = pe_raw(c - C_, l);
      }
      xT[4*g + r2][c] = f2bf(lrelu(xv));
    }
  }
  __syncthreads();
  f32x4 z4 = {0.f,0.f,0.f,0.f};
  f32x4 acc[8];
  #pragma unroll
  for (int i = 0; i < 8; i++) acc[i] = z4;
  #pragma unroll
  for (int t = 0; t < 3; t++){
    #pragma unroll
    for (int k0 = 0; k0 < 96; k0 += 32){
      bh8 bfr[2];
      #pragma unroll
      for (int nt = 0; nt < 2; nt++)
        bfr[nt] = *(const bh8*)&xT[wid*32 + nt*16 + col + t + 3][k0 + quad*8];
      #pragma unroll
      for (int mt = 0; mt < 4; mt++){
        bh8 af = *(const bh8*)&wA[t][mt*16 + col][k0 + quad*8];
        #pragma unroll
        for (int nt = 0; nt < 2; nt++)
          acc[mt*2+nt] = __builtin_amdgcn_mfma_f32_16x16x32_bf16(af, bfr[nt], acc[mt*2+nt], 0,0,0);
      }
    }
  }
  #pragma unroll
  for (int mt = 0; mt < 4; mt++){
    int f0 = mt*16 + quad*4;
    float q0 = b0[f0], q1 = b0[f0+1], q2 = b0[f0+2], q3 = b0[f0+3];
    #pragma unroll
    for (int nt = 0; nt < 2; nt++){
      int l = l0 + wid*32 + nt*16 + col;
      f32x4 a = acc[mt*2+nt];
      uint2 o = { pk2(lrelu(a[0]+q0), lrelu(a[1]+q1)),
                  pk2(lrelu(a[2]+q2), lrelu(a[3]+q3)) };
      *(uint2*)&t1bf[((size_t)b*L_ + l)*64 + f0] = o;
    }
  }
}

// ---------------- conv_in2 (MFMA): x = conv1x1(xcat, in_ws) + 0.1*(conv3(leaky(t1), in_w1)+in_b1)
__global__ __launch_bounds__(256) void k_conv_in2(const float* __restrict__ codes,
    const float* __restrict__ wsp, const float* __restrict__ w1, const float* __restrict__ b1,
    const unsigned short* __restrict__ t1bf, float* __restrict__ x){
  int b = blockIdx.x, l0 = blockIdx.y*128, tid = threadIdx.x;
  int wid = tid>>6, lane = tid&63, col = lane&15, quad = lane>>4;
  __shared__ __attribute__((aligned(16))) unsigned short xT[128][96];
  __shared__ __attribute__((aligned(16))) unsigned short wsA[64][96];
  __shared__ __attribute__((aligned(16))) unsigned short w1A[3][64][72];
  for (int i = tid; i < 64*96; i += 256){
    int m = i / 96, cin = i % 96;
    wsA[m][cin] = (cin < CIN_) ? f2bf(wsp[(size_t)m*CIN_ + cin]) : (unsigned short)0;
  }
  for (int i = tid; i < 64*64; i += 256){
    int m = i >> 6, cin = i & 63;
    const float* s = w1 + (size_t)m*192 + cin*3;
    w1A[0][m][cin] = f2bf(s[0]); w1A[1][m][cin] = f2bf(s[1]); w1A[2][m][cin] = f2bf(s[2]);
  }
  const float* cb = codes + (size_t)b*C_*L_;
  for (int i = tid; i < 96*32; i += 256){
    int c = i / 32, g = i % 32;
    int lg = l0 + 4*g;
    #pragma unroll
    for (int r2 = 0; r2 < 4; r2++){
      int l = lg + r2;
      float xv;
      if (c < C_) xv = cb[(size_t)c*L_ + l];
      else if (c < CIN_) xv = pe_raw(c - C_, l);
      else xv = 0.f;
      xT[4*g + r2][c] = f2bf(xv);
    }
  }
  __syncthreads();
  f32x4 z4 = {0.f,0.f,0.f,0.f};
  f32x4 accS[8], accD[8];
  #pragma unroll
  for (int i = 0; i < 8; i++){ accS[i] = z4; accD[i] = z4; }
  #pragma unroll
  for (int k0 = 0; k0 < 96; k0 += 32){
    bh8 bfr[2];
    #pragma unroll
    for (int nt = 0; nt < 2; nt++)
      bfr[nt] = *(const bh8*)&xT[wid*32 + nt*16 + col][k0 + quad*8];
    #pragma unroll
    for (int mt = 0; mt < 4; mt++){
      bh8 af = *(const bh8*)&wsA[mt*16 + col][k0 + quad*8];
      #pragma unroll
      for (int nt = 0; nt < 2; nt++)
        accS[mt*2+nt] = __builtin_amdgcn_mfma_f32_16x16x32_bf16(af, bfr[nt], accS[mt*2+nt], 0,0,0);
    }
  }
  bh8 zz8 = {0,0,0,0,0,0,0,0};
  #pragma unroll
  for (int t = 0; t < 3; t++){
    #pragma unroll
    for (int k0 = 0; k0 < 64; k0 += 32){
      bh8 bfr[2];
      #pragma unroll
      for (int nt = 0; nt < 2; nt++){
        int l = l0 + wid*32 + nt*16 + col + t - 1;
        bfr[nt] = (l >= 0 && l < L_)
          ? *(const bh8*)&t1bf[((size_t)b*L_ + l)*64 + k0 + quad*8] : zz8;
      }
      #pragma unroll
      for (int mt = 0; mt < 4; mt++){
        bh8 af = *(const bh8*)&w1A[t][mt*16 + col][k0 + quad*8];
        #pragma unroll
        for (int nt = 0; nt < 2; nt++)
          accD[mt*2+nt] = __builtin_amdgcn_mfma_f32_16x16x32_bf16(af, bfr[nt], accD[mt*2+nt], 0,0,0);
      }
    }
  }
  #pragma unroll
  for (int mt = 0; mt < 4; mt++){
    int f0 = mt*16 + quad*4;
    float q0 = b1[f0], q1 = b1[f0+1], q2 = b1[f0+2], q3 = b1[f0+3];
    #pragma unroll
    for (int nt = 0; nt < 2; nt++){
      int l = l0 + wid*32 + nt*16 + col;
      f32x4 s = accS[mt*2+nt], d = accD[mt*2+nt];
      size_t base = ((size_t)b*C_ + f0)*L_ + l;
      x[base]        = s[0] + 0.1f*(d[0] + q0);
      x[base + L_]   = s[1] + 0.1f*(d[1] + q1);
      x[base + 2*L_] = s[2] + 0.1f*(d[2] + q2);
      x[base + 3*L_] = s[3] + 0.1f*(d[3] + q3);
    }
  }
}

// ---------------- fused 8-iteration hypernet loop, x-resident-in-registers version.
// One block per b, 8 waves, __launch_bounds__(512,1) (1 block/CU -> 256-reg cap).
// Thread (wid,lane) owns x[g*8+wid][lane*8..+8] for g=0..7 (64 VGPRs), so the
// 8-iteration x RMW never touches global (saves 536 MB HBM); p stays L2-resident.
// Per iter: 2x { phaseA (sobel from regs, write T) | barrier | GEMM1 | barrier },
// h_t epilogue + GEMM2 (intra-wave), barrier, U(=f32 LDS alias) update-scatter,
// barrier, gather-add into x regs, barrier.
#define GSTR 16408   // u16 stride between sobel-groups in T (32*512 + 24 pad)
#define CHUNK(G) { \
      f32x8 r = xr[G]; \
      float s1 = 0.f, s2 = 0.f; \
      _Pragma("unroll") \
      for (int i = 0; i < 8; i++){ s1 += r[i]; s2 += r[i]*r[i]; } \
      _Pragma("unroll") \
      for (int m = 32; m; m >>= 1){ s1 += __shfl_xor(s1, m); s2 += __shfl_xor(s2, m); } \
      const float mean = s1 * (1.f/512.f); \
      const float rstd = rsqrtf(s2*(1.f/512.f) - mean*mean + 1e-5f); \
      const int toff = (((G)&3)*8 + wid)*512 + lane*8; \
      float xn[8]; \
      _Pragma("unroll") \
      for (int i = 0; i < 8; i++) xn[i] = (r[i]-mean)*rstd; \
      *(uint4*)&Tbuf[toff] = pk8(xn); \
      float A[8], Bv[8]; \
      A[0] = 2.f*xn[0]+xn[1]; Bv[0] = xn[1]; \
      _Pragma("unroll") \
      for (int i = 1; i < 7; i++){ A[i] = xn[i-1]+2.f*xn[i]+xn[i+1]; Bv[i] = xn[i+1]-xn[i-1]; } \
      A[7] = xn[6]+2.f*xn[7]; Bv[7] = -xn[6]; \
      float Cv[8], Dv[8], Ev[8]; \
      _Pragma("unroll") \
      for (int i = 0; i < 8; i++){ \
        float am = shf(A[i], lmA)*wm, ap = shf(A[i], lpA)*wp; \
        Cv[i] = am + 2.f*A[i] + ap; \
        Dv[i] = ap - am; \
        float bm = shf(Bv[i], lmA)*wm, bp = shf(Bv[i], lpA)*wp; \
        Ev[i] = bm + 2.f*Bv[i] + bp; \
      } \
      float g0[8], g1[8], g2[8]; \
      _Pragma("unroll") \
      for (int i = 0; i < 8; i++){ \
        g0[i] = __sinf(shf(Cv[i], zpA)*qp - shf(Cv[i], zmA)*qm); \
        g1[i] = __sinf(shf(Dv[i], zmA)*qm + 2.f*Dv[i] + shf(Dv[i], zpA)*qp); \
        g2[i] = __sinf(shf(Ev[i], zmA)*qm + 2.f*Ev[i] + shf(Ev[i], zpA)*qp); \
      } \
      *(uint4*)&Tbuf[GSTR   + toff] = pk8(g0); \
      *(uint4*)&Tbuf[2*GSTR + toff] = pk8(g1); \
      *(uint4*)&Tbuf[3*GSTR + toff] = pk8(g2); \
    }

__global__ __launch_bounds__(512, 1) void k_loop(float* __restrict__ x,
    const unsigned short* __restrict__ p_bf, const float* __restrict__ leak){
  const int b = blockIdx.x, tid = threadIdx.x;
  const int wid = tid >> 6, lane = tid & 63, col = lane & 15, quad = lane >> 4;
  const int yy = lane & 7, zz = lane >> 3;
  const unsigned short* pb = p_bf + (size_t)b*PT_;
  float* xb = x + (size_t)b*C_*L_;

  __shared__ __attribute__((aligned(16))) unsigned short Tbuf[4*GSTR];  // 131,264 B
  unsigned short (*h_t)[72] = (unsigned short (*)[72])Tbuf;             // 73,728 B alias
  float* U = (float*)Tbuf;                                              // 131,072 B alias

  const int lmA = ((yy > 0) ? lane-1 : lane)*4;  const float wm = (yy > 0) ? 1.f : 0.f;
  const int lpA = ((yy < 7) ? lane+1 : lane)*4;  const float wp = (yy < 7) ? 1.f : 0.f;
  const int zmA = ((zz > 0) ? lane-8 : lane)*4;  const float qm = (zz > 0) ? 1.f : 0.f;
  const int zpA = ((zz < 7) ? lane+8 : lane)*4;  const float qp = (zz < 7) ? 1.f : 0.f;

  const float lk = fminf(fmaxf(leak[0], 0.001f), 1000.f);
  const f32x4 z4 = {0.f,0.f,0.f,0.f};

  // ---- load x slice into registers (static indices only — rule #20)
  f32x8 xr[8];
  #pragma unroll
  for (int g = 0; g < 8; g++){
    const float* s = xb + (size_t)(g*8 + wid)*L_ + lane*8;
    float4 a = *(const float4*)s, c = *(const float4*)(s + 4);
    f32x8 v = {a.x,a.y,a.z,a.w,c.x,c.y,c.z,c.w};
    xr[g] = v;
  }

  for (int it = 0; it < 8; ++it){
    f32x4 acc1[32];                      // [mt 0..3]=wh-part, [mt 4..7]=ws-part
    #pragma unroll
    for (int i = 0; i < 32; i++) acc1[i] = z4;

    #pragma unroll
    for (int h = 0; h < 2; ++h){
      // ---- phase A: channels h*32 .. h*32+31, from registers, shfl-only exchange
      if (h == 0){ CHUNK(0) CHUNK(1) CHUNK(2) CHUNK(3) }
      else       { CHUNK(4) CHUNK(5) CHUNK(6) CHUNK(7) }
      __syncthreads();
      // ---- GEMM1 partial: phys k = quad*64 + h*32 + kt*8 + j  (p is L2-resident)
      #pragma unroll
      for (int kt = 0; kt < 4; ++kt){
        bh8 bfr[4];
        #pragma unroll
        for (int nt = 0; nt < 4; nt++){
          const int n = wid*64 + nt*16 + col;
          bh8 fv;
          #pragma unroll
          for (int j = 0; j < 8; j++) fv[j] = (short)Tbuf[quad*GSTR + (kt*8+j)*512 + n];
          bfr[nt] = fv;
        }
        const int kof = quad*64 + h*32 + kt*8;
        #pragma unroll
        for (int mt = 0; mt < 8; mt++){
          bh8 af = (mt < 4)
            ? *(const bh8*)&pb[(size_t)(mt*16+col)*256 + kof]
            : *(const bh8*)&pb[OFF_WS + (size_t)((mt-4)*16+col)*256 + kof];
          #pragma unroll
          for (int nt = 0; nt < 4; nt++)
            acc1[mt*4+nt] = __builtin_amdgcn_mfma_f32_16x16x32_bf16(af, bfr[nt], acc1[mt*4+nt], 0,0,0);
        }
      }
      __syncthreads();
    }

    // ---- h epilogue -> h_t (writer and reader rows within the same wave)
    #pragma unroll
    for (int mt = 0; mt < 4; mt++){
      const int f0 = mt*16 + quad*4;
      const float bh0 = bf2f(pb[OFF_BH+f0]),   bh1 = bf2f(pb[OFF_BH+f0+1]);
      const float bh2 = bf2f(pb[OFF_BH+f0+2]), bh3 = bf2f(pb[OFF_BH+f0+3]);
      #pragma unroll
      for (int nt = 0; nt < 4; nt++){
        const int n = wid*64 + nt*16 + col;
        f32x4 a = acc1[mt*4+nt];
        uint2 o = { pk2(lrelu(a[0]+bh0), lrelu(a[1]+bh1)),
                    pk2(lrelu(a[2]+bh2), lrelu(a[3]+bh3)) };
        *(uint2*)&h_t[n][f0] = o;
      }
    }
    // ---- GEMM2: wl @ h (intra-wave LDS, DS pipe in-order -> no barrier)
    f32x4 acc2[16];
    #pragma unroll
    for (int i = 0; i < 16; i++) acc2[i] = z4;
    #pragma unroll
    for (int k0 = 0; k0 < 64; k0 += 32){
      bh8 hb[4];
      #pragma unroll
      for (int nt = 0; nt < 4; nt++)
        hb[nt] = *(const bh8*)&h_t[wid*64 + nt*16 + col][k0 + quad*8];
      #pragma unroll
      for (int mt = 0; mt < 4; mt++){
        bh8 al = *(const bh8*)&pb[OFF_WL + (size_t)(mt*16 + col)*64 + k0 + quad*8];
        #pragma unroll
        for (int nt = 0; nt < 4; nt++)
          acc2[mt*4+nt] = __builtin_amdgcn_mfma_f32_16x16x32_bf16(al, hb[nt], acc2[mt*4+nt], 0,0,0);
      }
    }
    __syncthreads();   // all waves done reading h_t before U overwrites Tbuf
    // ---- scatter update values to U[c][s] (f32)
    #pragma unroll
    for (int mt = 0; mt < 4; mt++){
      const int f0 = mt*16 + quad*4;
      const float bs0 = bf2f(pb[OFF_BS+f0]),   bs1 = bf2f(pb[OFF_BS+f0+1]);
      const float bs2 = bf2f(pb[OFF_BS+f0+2]), bs3 = bf2f(pb[OFF_BS+f0+3]);
      const float bl0 = bf2f(pb[OFF_BL+f0]),   bl1 = bf2f(pb[OFF_BL+f0+1]);
      const float bl2 = bf2f(pb[OFF_BL+f0+2]), bl3 = bf2f(pb[OFF_BL+f0+3]);
      #pragma unroll
      for (int nt = 0; nt < 4; nt++){
        const int s = wid*64 + nt*16 + col;
        f32x4 xs = acc1[(mt+4)*4+nt], dx = acc2[mt*4+nt];
        U[(size_t)(f0+0)*512 + s] = lk*(xs[0] + bs0 + 0.1f*(dx[0] + bl0));
        U[(size_t)(f0+1)*512 + s] = lk*(xs[1] + bs1 + 0.1f*(dx[1] + bl1));
        U[(size_t)(f0+2)*512 + s] = lk*(xs[2] + bs2 + 0.1f*(dx[2] + bl2));
        U[(size_t)(f0+3)*512 + s] = lk*(xs[3] + bs3 + 0.1f*(dx[3] + bl3));
      }
    }
    __syncthreads();
    // ---- gather-add into x registers (wave reads contiguous 2KB rows)
    #pragma unroll
    for (int g = 0; g < 8; g++){
      const float* us = &U[(size_t)(g*8 + wid)*512 + lane*8];
      float4 a = *(const float4*)us, c = *(const float4*)(us + 4);
      f32x8 add = {a.x,a.y,a.z,a.w,c.x,c.y,c.z,c.w};
      xr[g] += add;
    }
    __syncthreads();   // Tbuf free for next iteration's phase A
  }

  // ---- write x back
  #pragma unroll
  for (int g = 0; g < 8; g++){
    float* s = xb + (size_t)(g*8 + wid)*L_ + lane*8;
    f32x8 v = xr[g];
    float4 a = {v[0],v[1],v[2],v[3]}, c = {v[4],v[5],v[6],v[7]};
    *(float4*)s = a; *(float4*)(s + 4) = c;
  }
}

// ---------------- conv_out1 (MFMA): t1bf = bf16(lrelu(conv3(leaky(x), out_w0)+out_b0))
__global__ __launch_bounds__(256) void k_conv_out1(const float* __restrict__ x,
    const float* __restrict__ w, const float* __restrict__ bias,
    unsigned short* __restrict__ t1bf){
  int b = blockIdx.x, l0 = blockIdx.y*128, tid = threadIdx.x;
  int wid = tid>>6, lane = tid&63, col = lane&15, quad = lane>>4;
  __shared__ __attribute__((aligned(16))) unsigned short xT[136][72];
  __shared__ __attribute__((aligned(16))) unsigned short wA[3][64][72];
  for (int i = tid; i < 64*64; i += 256){
    int m = i >> 6, cin = i & 63;
    const float* s = w + (size_t)m*192 + cin*3;
    wA[0][m][cin] = f2bf(s[0]); wA[1][m][cin] = f2bf(s[1]); wA[2][m][cin] = f2bf(s[2]);
  }
  const float* xb = x + (size_t)b*C_*L_;
  for (int i = tid; i < 64*34; i += 256){
    int c = i / 34, g = i % 34;
    int lg = l0 - 4 + 4*g;
    if (lg >= 0 && lg + 3 < L_){
      float4 f = *(const float4*)&xb[(size_t)c*L_ + lg];
      xT[4*g  ][c] = f2bf(lrelu(f.x));
      xT[4*g+1][c] = f2bf(lrelu(f.y));
      xT[4*g+2][c] = f2bf(lrelu(f.z));
      xT[4*g+3][c] = f2bf(lrelu(f.w));
    } else {
      #pragma unroll
      for (int r2 = 0; r2 < 4; r2++){
        int l = lg + r2;
        float v = (l >= 0 && l < L_) ? xb[(size_t)c*L_ + l] : 0.f;
        xT[4*g + r2][c] = f2bf(lrelu(v));
      }
    }
  }
  __syncthreads();
  f32x4 z4 = {0.f,0.f,0.f,0.f};
  f32x4 acc[8];
  #pragma unroll
  for (int i = 0; i < 8; i++) acc[i] = z4;
  #pragma unroll
  for (int t = 0; t < 3; t++){
    #pragma unroll
    for (int k0 = 0; k0 < 64; k0 += 32){
      bh8 bfr[2];
      #pragma unroll
      for (int nt = 0; nt < 2; nt++)
        bfr[nt] = *(const bh8*)&xT[wid*32 + nt*16 + col + t + 3][k0 + quad*8];
      #pragma unroll
      for (int mt = 0; mt < 4; mt++){
        bh8 af = *(const bh8*)&wA[t][mt*16 + col][k0 + quad*8];
        #pragma unroll
        for (int nt = 0; nt < 2; nt++)
          acc[mt*2+nt] = __builtin_amdgcn_mfma_f32_16x16x32_bf16(af, bfr[nt], acc[mt*2+nt], 0,0,0);
      }
    }
  }
  #pragma unroll
  for (int mt = 0; mt < 4; mt++){
    int f0 = mt*16 + quad*4;
    float q0 = bias[f0], q1 = bias[f0+1], q2 = bias[f0+2], q3 = bias[f0+3];
    #pragma unroll
    for (int nt = 0; nt < 2; nt++){
      int l = l0 + wid*32 + nt*16 + col;
      f32x4 a = acc[mt*2+nt];
      uint2 o = { pk2(lrelu(a[0]+q0), lrelu(a[1]+q1)),
                  pk2(lrelu(a[2]+q2), lrelu(a[3]+q3)) };
      *(uint2*)&t1bf[((size_t)b*L_ + l)*64 + f0] = o;
    }
  }
}

// ---------------- conv_out2 (MFMA): x += 0.1*(conv3(leaky(t1), out_w1)+out_b1)
__global__ __launch_bounds__(256) void k_conv_out2(float* __restrict__ x,
    const unsigned short* __restrict__ t1bf, const float* __restrict__ w,
    const float* __restrict__ bias){
  int b = blockIdx.x, l0 = blockIdx.y*256, tid = threadIdx.x;
  int wid = tid>>6, lane = tid&63, col = lane&15, quad = lane>>4;
  __shared__ __attribute__((aligned(16))) unsigned short wA[3][64][72];
  for (int i = tid; i < 64*64; i += 256){
    int m = i >> 6, cin = i & 63;
    const float* s = w + (size_t)m*192 + cin*3;
    wA[0][m][cin] = f2bf(s[0]); wA[1][m][cin] = f2bf(s[1]); wA[2][m][cin] = f2bf(s[2]);
  }
  __syncthreads();
  f32x4 z4 = {0.f,0.f,0.f,0.f};
  f32x4 acc[16];
  #pragma unroll
  for (int i = 0; i < 16; i++) acc[i] = z4;
  bh8 zz8 = {0,0,0,0,0,0,0,0};
  #pragma unroll
  for (int t = 0; t < 3; t++){
    #pragma unroll
    for (int k0 = 0; k0 < 64; k0 += 32){
      bh8 bfr[4];
      #pragma unroll
      for (int nt = 0; nt < 4; nt++){
        int l = l0 + wid*64 + nt*16 + col + t - 1;
        bfr[nt] = (l >= 0 && l < L_)
          ? *(const bh8*)&t1bf[((size_t)b*L_ + l)*64 + k0 + quad*8] : zz8;
      }
      #pragma unroll
      for (int mt = 0; mt < 4; mt++){
        bh8 af = *(const bh8*)&wA[t][mt*16 + col][k0 + quad*8];
        #pragma unroll
        for (int nt = 0; nt < 4; nt++)
          acc[mt*4+nt] = __builtin_amdgcn_mfma_f32_16x16x32_bf16(af, bfr[nt], acc[mt*4+nt], 0,0,0);
      }
    }
  }
  #pragma unroll
  for (int mt = 0; mt < 4; mt++){
    int f0 = mt*16 + quad*4;
    float q0 = bias[f0], q1 = bias[f0+1], q2 = bias[f0+2], q3 = bias[f0+3];
    #pragma unroll
    for (int nt = 0; nt < 4; nt++){
      int l = l0 + wid*64 + nt*16 + col;
      f32x4 a = acc[mt*4+nt];
      size_t base = ((size_t)b*C_ + f0)*L_ + l;
      x[base]        += 0.1f*(a[0] + q0);
      x[base + L_]   += 0.1f*(a[1] + q1);
      x[base + 2*L_] += 0.1f*(a[2] + q2);
      x[base + 3*L_] += 0.1f*(a[3] + q3);
    }
  }
}

// ---------------- loss: cross-entropy vs argmax(codes)
__global__ __launch_bounds__(256) void k_loss(const float* __restrict__ x,
    const float* __restrict__ codes, float* __restrict__ out){
  int b = blockIdx.x;
  int l = blockIdx.y*256 + threadIdx.x;
  const float* xb = x + (size_t)b*C_*L_ + l;
  const float* cb = codes + (size_t)b*C_*L_ + l;
  float m = -1e30f, cm = -1e30f;
  int ci = 0;
  for (int c = 0; c < C_; c++){
    float xv = xb[(size_t)c*L_];
    m = fmaxf(m, xv);
    float cv = cb[(size_t)c*L_];
    if (cv > cm){ cm = cv; ci = c; }
  }
  float s = 0.f, vi = 0.f;
  for (int c = 0; c < C_; c++){
    float xv = xb[(size_t)c*L_];
    s += expf(xv - m);
    if (c == ci) vi = xv;
  }
  float lp = vi - m - logf(s);
  __shared__ float red[256];
  red[threadIdx.x] = -lp; __syncthreads();
  for (int sft = 128; sft; sft >>= 1){
    if (threadIdx.x < sft) red[threadIdx.x] += red[threadIdx.x + sft];
    __syncthreads();
  }
  if (threadIdx.x == 0) atomicAdd(out + B_*L_, red[0] * (1.0f/131072.0f));
}

// ---------------- lat head (MFMA): two 64x64 GEMMs per (b, 256-col tile) + lat2 reduce
__global__ __launch_bounds__(256) void k_lat(const float* __restrict__ x,
    const float* __restrict__ w10, const float* __restrict__ b10,
    const float* __restrict__ w11, const float* __restrict__ b11,
    const float* __restrict__ w20, const float* __restrict__ b20,
    const float* __restrict__ w21, const float* __restrict__ b21,
    const float* __restrict__ ws2, float* __restrict__ out){
  int b = blockIdx.x, l0 = blockIdx.y*256;
  int tid = threadIdx.x;
  int wid = tid >> 6, lane = tid & 63, col = lane & 15, quad = lane >> 4;
  __shared__ __attribute__((aligned(16))) unsigned short wA[2][64][72];
  __shared__ __attribute__((aligned(16))) unsigned short Bt[256][72];

  for (int i = tid; i < 1024; i += 256){
    int arr = i >> 9, rem = i & 511, row = rem >> 3, seg = rem & 7;
    const float* src = (arr ? w11 : w10) + (size_t)row*C_ + seg*8;
    *(bh8*)&wA[arr][row][seg*8] = cvt8(*(const float4*)src, *(const float4*)(src+4));
  }
  for (int i = tid; i < 4096; i += 256){
    int c = i >> 6, seg = i & 63;
    float4 v = *(const float4*)&x[((size_t)b*C_ + c)*L_ + l0 + seg*4];
    Bt[seg*4+0][c] = f2bf(lrelu(v.x));
    Bt[seg*4+1][c] = f2bf(lrelu(v.y));
    Bt[seg*4+2][c] = f2bf(lrelu(v.z));
    Bt[seg*4+3][c] = f2bf(lrelu(v.w));
  }
  __syncthreads();
  f32x4 z4 = {0.f,0.f,0.f,0.f};
  f32x4 acc1[16];
  #pragma unroll
  for (int i = 0; i < 16; i++) acc1[i] = z4;
  #pragma unroll
  for (int k0 = 0; k0 < 64; k0 += 32){
    bh8 bfr[4];
    #pragma unroll
    for (int nt = 0; nt < 4; nt++)
      bfr[nt] = *(const bh8*)&Bt[wid*64 + nt*16 + col][k0 + quad*8];
    #pragma unroll
    for (int mt = 0; mt < 4; mt++){
      bh8 af = *(const bh8*)&wA[0][mt*16 + col][k0 + quad*8];
      #pragma unroll
      for (int nt = 0; nt < 4; nt++)
        acc1[mt*4+nt] = __builtin_amdgcn_mfma_f32_16x16x32_bf16(af, bfr[nt], acc1[mt*4+nt], 0, 0, 0);
    }
  }
  #pragma unroll
  for (int mt = 0; mt < 4; mt++){
    int f0 = mt*16 + quad*4;
    f32x4 bv = *(const f32x4*)&b10[f0];
    #pragma unroll
    for (int nt = 0; nt < 4; nt++){
      int n = wid*64 + nt*16 + col;
      f32x4 a = acc1[mt*4+nt];
      uint2 o = { pk2(lrelu(a[0]+bv[0]), lrelu(a[1]+bv[1])),
                  pk2(lrelu(a[2]+bv[2]), lrelu(a[3]+bv[3])) };
      *(uint2*)&Bt[n][f0] = o;
    }
  }
  f32x4 acc2[16];
  #pragma unroll
  for (int i = 0; i < 16; i++) acc2[i] = z4;
  #pragma unroll
  for (int k0 = 0; k0 < 64; k0 += 32){
    bh8 bfr[4];
    #pragma unroll
    for (int nt = 0; nt < 4; nt++)
      bfr[nt] = *(const bh8*)&Bt[wid*64 + nt*16 + col][k0 + quad*8];
    #pragma unroll
    for (int mt = 0; mt < 4; mt++){
      bh8 af = *(const bh8*)&wA[1][mt*16 + col][k0 + quad*8];
      #pragma unroll
      for (int nt = 0; nt < 4; nt++)
        acc2[mt*4+nt] = __builtin_amdgcn_mfma_f32_16x16x32_bf16(af, bfr[nt], acc2[mt*4+nt], 0, 0, 0);
    }
  }
  float psA[4] = {0.f,0.f,0.f,0.f}, psB[4] = {0.f,0.f,0.f,0.f};
  #pragma unroll
  for (int mt = 0; mt < 4; mt++){
    int f0 = mt*16 + quad*4;
    f32x4 b11v = *(const f32x4*)&b11[f0];
    f32x4 wsv  = *(const f32x4*)&ws2[f0];
    f32x4 w20v = *(const f32x4*)&w20[f0];
    #pragma unroll
    for (int nt = 0; nt < 4; nt++){
      int lg = l0 + wid*64 + nt*16 + col;
      size_t base = ((size_t)b*C_ + f0)*L_ + lg;
      f32x4 a = acc2[mt*4+nt];
      #pragma unroll
      for (int r = 0; r < 4; r++){
        float xv = x[base + (size_t)r*L_];
        float lat = xv + 0.1f*(a[r] + b11v[r]);
        psA[nt] += wsv[r]*lat;
        psB[nt] += w20v[r]*lrelu(lat);
      }
    }
  }
  #pragma unroll
  for (int nt = 0; nt < 4; nt++){
    psA[nt] += __shfl_xor(psA[nt], 16); psA[nt] += __shfl_xor(psA[nt], 32);
    psB[nt] += __shfl_xor(psB[nt], 16); psB[nt] += __shfl_xor(psB[nt], 32);
  }
  if (quad == 0){
    float b20s = b20[0], w21s = w21[0], b21s = b21[0];
    #pragma unroll
    for (int nt = 0; nt < 4; nt++){
      float dx2 = w21s*lrelu(psB[nt] + b20s) + b21s;
      out[(size_t)b*L_ + l0 + wid*64 + nt*16 + col] = psA[nt] + 0.1f*dx2;
    }
  }
}

extern "C" void kernel_launch(void* const* d_in, const int* in_sizes, int n_in,
                              void* d_out, int out_size, void* d_ws, size_t ws_size,
                              hipStream_t stream) {
  (void)in_sizes; (void)n_in; (void)out_size; (void)ws_size;
  const float* codes   = (const float*)d_in[0];
  const int*   y       = (const int*)  d_in[1];
  const float* fc_w    = (const float*)d_in[2];
  const float* fc_b    = (const float*)d_in[3];
  const float* in_w0   = (const float*)d_in[4];
  const float* in_b0   = (const float*)d_in[5];
  const float* in_w1   = (const float*)d_in[6];
  const float* in_b1   = (const float*)d_in[7];
  const float* in_wsp  = (const float*)d_in[8];
  const float* leak    = (const float*)d_in[9];
  const float* hyper_w = (const float*)d_in[10];
  const float* hyper_b = (const float*)d_in[11];
  const float* out_w0  = (const float*)d_in[12];
  const float* out_b0  = (const float*)d_in[13];
  const float* out_w1  = (const float*)d_in[14];
  const float* out_b1  = (const float*)d_in[15];
  const float* l1_w0   = (const float*)d_in[16];
  const float* l1_b0   = (const float*)d_in[17];
  const float* l1_w1   = (const float*)d_in[18];
  const float* l1_b1   = (const float*)d_in[19];
  const float* l2_w0   = (const float*)d_in[20];
  const float* l2_b0   = (const float*)d_in[21];
  const float* l2_w1   = (const float*)d_in[22];
  const float* l2_b1   = (const float*)d_in[23];
  const float* l2_ws   = (const float*)d_in[24];
  float* out = (float*)d_out;

  char* ws = (char*)d_ws;
  unsigned short* p_bf = (unsigned short*)(ws);              // 256*37056*2 = 18,972,672
  unsigned short* ybf  = (unsigned short*)(ws + 18972672);   // 131,072
  float* x             = (float*)(ws + 19103744);            // 33,554,432
  unsigned short* t1bf = (unsigned short*)(ws + 52658176);   // 16,777,216

  k_yemb<<<B_, 256, 0, stream>>>(fc_w, fc_b, y, ybf, out);
  k_hyper<<<PT_/64, 256, 0, stream>>>(hyper_w, hyper_b, ybf, p_bf);
  k_conv_in1<<<dim3(B_, 4), 256, 0, stream>>>(codes, in_w0, in_b0, t1bf);
  k_conv_in2<<<dim3(B_, 4), 256, 0, stream>>>(codes, in_wsp, in_w1, in_b1, t1bf, x);
  k_loop<<<B_, 512, 0, stream>>>(x, p_bf, leak);
  k_conv_out1<<<dim3(B_, 4), 256, 0, stream>>>(x, out_w0, out_b0, t1bf);
  k_conv_out2<<<dim3(B_, 2), 256, 0, stream>>>(x, t1bf, out_w1, out_b1);
  k_loss<<<dim3(B_, 2), 256, 0, stream>>>(x, codes, out);
  k_lat<<<dim3(B_, 2), 256, 0, stream>>>(x, l1_w0, l1_b0, l1_w1, l1_b1,
                                         l2_w0, l2_b0, l2_w1, l2_b1, l2_ws, out);
}

// Round 6
// 855.814 us; speedup vs baseline: 1.3145x; 1.3145x over previous
//
#include <hip/hip_runtime.h>

#define B_ 256
#define C_ 64
#define L_ 512
#define CIN_ 82
#define NFREQ_ 9
#define EMB_ 256
#define NLAB_ 10
#define PT_ 37056
#define OFF_BH 16384
#define OFF_WL 16448
#define OFF_BL 20544
#define OFF_WS 20608
#define OFF_BS 36992
#define PI_F 3.14159265358979323846f

typedef short bh8 __attribute__((ext_vector_type(8)));   // 8 bf16 (raw bits)
typedef float f32x4 __attribute__((ext_vector_type(4)));

__device__ inline float lrelu(float v){ return v > 0.f ? v : 0.2f*v; }

__device__ inline unsigned short f2bf(float f){
  unsigned u = __float_as_uint(f);
  u += 0x7FFFu + ((u >> 16) & 1u);      // RNE
  return (unsigned short)(u >> 16);
}
__device__ inline float bf2f(unsigned short u){
  return __uint_as_float((unsigned)u << 16);
}
__device__ inline unsigned pk2(float a, float b){
  return (unsigned)f2bf(a) | ((unsigned)f2bf(b) << 16);
}
__device__ inline bh8 cvt8(float4 a, float4 b){
  bh8 r;
  r[0]=(short)f2bf(a.x); r[1]=(short)f2bf(a.y); r[2]=(short)f2bf(a.z); r[3]=(short)f2bf(a.w);
  r[4]=(short)f2bf(b.x); r[5]=(short)f2bf(b.y); r[6]=(short)f2bf(b.z); r[7]=(short)f2bf(b.w);
  return r;
}
__device__ inline uint4 pk8(const float* v){
  uint4 o = { pk2(v[0],v[1]), pk2(v[2],v[3]), pk2(v[4],v[5]), pk2(v[6],v[7]) };
  return o;
}
// in-wave lane fetch via LDS-pipe permute (addr = src_lane*4)
__device__ inline float shf(float v, int a){
  return __uint_as_float((unsigned)__builtin_amdgcn_ds_bpermute(a, (int)__float_as_uint(v)));
}

// ---------------- yemb: normalize(fc_w[:,y]+fc_b) -> bf16 [b][e]; zero loss slot
__global__ __launch_bounds__(256) void k_yemb(const float* __restrict__ fc_w,
    const float* __restrict__ fc_b, const int* __restrict__ y,
    unsigned short* __restrict__ ybf, float* __restrict__ out){
  int b = blockIdx.x, e = threadIdx.x;
  int lab = y[b];
  float v = fc_w[e*NLAB_ + lab] + fc_b[e];
  __shared__ float red[256];
  red[e] = v*v; __syncthreads();
  for (int s = 128; s; s >>= 1){ if (e < s) red[e] += red[e+s]; __syncthreads(); }
  float nrm = fmaxf(sqrtf(red[0]), 1e-12f);
  ybf[(size_t)b*EMB_ + e] = f2bf(v / nrm);
  if (b == 0 && e == 0) out[B_*L_] = 0.f;
}

// ---------------- hyper (MFMA): p_bf[b][j] = bf16(yemb[b][:] . hw[j][:] + hb[j])
__global__ __launch_bounds__(256) void k_hyper(const float* __restrict__ hw,
    const float* __restrict__ hb, const unsigned short* __restrict__ ybf,
    unsigned short* __restrict__ p_bf){
  int tid = threadIdx.x;
  int wid = tid >> 6, lane = tid & 63, col = lane & 15, quad = lane >> 4;
  int j = blockIdx.x*64 + wid*16 + col;
  f32x4 acc[16];
  f32x4 z4 = {0.f,0.f,0.f,0.f};
  #pragma unroll
  for (int i = 0; i < 16; i++) acc[i] = z4;
  for (int k0 = 0; k0 < 256; k0 += 32){
    const float* hp = hw + (size_t)j*EMB_ + k0 + quad*8;
    bh8 bf = cvt8(*(const float4*)hp, *(const float4*)(hp+4));
    #pragma unroll
    for (int mt = 0; mt < 16; mt++){
      bh8 af = *(const bh8*)&ybf[(size_t)(mt*16 + col)*EMB_ + k0 + quad*8];
      acc[mt] = __builtin_amdgcn_mfma_f32_16x16x32_bf16(af, bf, acc[mt], 0, 0, 0);
    }
  }
  float hbv = hb[j];
  #pragma unroll
  for (int mt = 0; mt < 16; mt++){
    int b0 = mt*16 + quad*4;
    #pragma unroll
    for (int r = 0; r < 4; r++)
      p_bf[(size_t)(b0 + r)*PT_ + j] = f2bf(acc[mt][r] + hbv);
  }
}

// positional encoding value (raw)
__device__ inline float pe_raw(int fi, int l){
  if (fi < NFREQ_) return __sinf(PI_F / (float)(1 << fi) * (float)l);
  return __cosf(PI_F / (float)(1 << (fi - NFREQ_)) * (float)l);
}

// ---------------- conv_in1 (MFMA): t1bf[b][l][m] = bf16(lrelu(conv3(leaky(xcat), in_w0)+in_b0))
__global__ __launch_bounds__(256) void k_conv_in1(const float* __restrict__ codes,
    const float* __restrict__ w0, const float* __restrict__ b0,
    unsigned short* __restrict__ t1bf){
  int b = blockIdx.x, l0 = blockIdx.y*128, tid = threadIdx.x;
  int wid = tid>>6, lane = tid&63, col = lane&15, quad = lane>>4;
  __shared__ __attribute__((aligned(16))) unsigned short xT[136][96];
  __shared__ __attribute__((aligned(16))) unsigned short wA[3][64][96];
  for (int i = tid; i < 64*96; i += 256){
    int m = i / 96, cin = i % 96;
    if (cin < CIN_){
      const float* s = w0 + (size_t)m*(CIN_*3) + cin*3;
      wA[0][m][cin] = f2bf(s[0]); wA[1][m][cin] = f2bf(s[1]); wA[2][m][cin] = f2bf(s[2]);
    } else { wA[0][m][cin] = 0; wA[1][m][cin] = 0; wA[2][m][cin] = 0; }
  }
  const float* cb = codes + (size_t)b*C_*L_;
  for (int i = tid; i < 96*34; i += 256){
    int c = i / 34, g = i % 34;
    int lg = l0 - 4 + 4*g;
    #pragma unroll
    for (int r2 = 0; r2 < 4; r2++){
      int l = lg + r2;
      float xv = 0.f;
      if (l >= 0 && l < L_){
        if (c < C_) xv = cb[(size_t)c*L_ + l];
        else if (c < CIN_) xv = pe_raw(c - C_, l);
      }
      xT[4*g + r2][c] = f2bf(lrelu(xv));
    }
  }
  __syncthreads();
  f32x4 z4 = {0.f,0.f,0.f,0.f};
  f32x4 acc[8];
  #pragma unroll
  for (int i = 0; i < 8; i++) acc[i] = z4;
  #pragma unroll
  for (int t = 0; t < 3; t++){
    #pragma unroll
    for (int k0 = 0; k0 < 96; k0 += 32){
      bh8 bfr[2];
      #pragma unroll
      for (int nt = 0; nt < 2; nt++)
        bfr[nt] = *(const bh8*)&xT[wid*32 + nt*16 + col + t + 3][k0 + quad*8];
      #pragma unroll
      for (int mt = 0; mt < 4; mt++){
        bh8 af = *(const bh8*)&wA[t][mt*16 + col][k0 + quad*8];
        #pragma unroll
        for (int nt = 0; nt < 2; nt++)
          acc[mt*2+nt] = __builtin_amdgcn_mfma_f32_16x16x32_bf16(af, bfr[nt], acc[mt*2+nt], 0,0,0);
      }
    }
  }
  #pragma unroll
  for (int mt = 0; mt < 4; mt++){
    int f0 = mt*16 + quad*4;
    float q0 = b0[f0], q1 = b0[f0+1], q2 = b0[f0+2], q3 = b0[f0+3];
    #pragma unroll
    for (int nt = 0; nt < 2; nt++){
      int l = l0 + wid*32 + nt*16 + col;
      f32x4 a = acc[mt*2+nt];
      uint2 o = { pk2(lrelu(a[0]+q0), lrelu(a[1]+q1)),
                  pk2(lrelu(a[2]+q2), lrelu(a[3]+q3)) };
      *(uint2*)&t1bf[((size_t)b*L_ + l)*64 + f0] = o;
    }
  }
}

// ---------------- conv_in2 (MFMA): x = conv1x1(xcat, in_ws) + 0.1*(conv3(leaky(t1), in_w1)+in_b1)
__global__ __launch_bounds__(256) void k_conv_in2(const float* __restrict__ codes,
    const float* __restrict__ wsp, const float* __restrict__ w1, const float* __restrict__ b1,
    const unsigned short* __restrict__ t1bf, float* __restrict__ x){
  int b = blockIdx.x, l0 = blockIdx.y*128, tid = threadIdx.x;
  int wid = tid>>6, lane = tid&63, col = lane&15, quad = lane>>4;
  __shared__ __attribute__((aligned(16))) unsigned short xT[128][96];
  __shared__ __attribute__((aligned(16))) unsigned short wsA[64][96];
  __shared__ __attribute__((aligned(16))) unsigned short w1A[3][64][72];
  for (int i = tid; i < 64*96; i += 256){
    int m = i / 96, cin = i % 96;
    wsA[m][cin] = (cin < CIN_) ? f2bf(wsp[(size_t)m*CIN_ + cin]) : (unsigned short)0;
  }
  for (int i = tid; i < 64*64; i += 256){
    int m = i >> 6, cin = i & 63;
    const float* s = w1 + (size_t)m*192 + cin*3;
    w1A[0][m][cin] = f2bf(s[0]); w1A[1][m][cin] = f2bf(s[1]); w1A[2][m][cin] = f2bf(s[2]);
  }
  const float* cb = codes + (size_t)b*C_*L_;
  for (int i = tid; i < 96*32; i += 256){
    int c = i / 32, g = i % 32;
    int lg = l0 + 4*g;
    #pragma unroll
    for (int r2 = 0; r2 < 4; r2++){
      int l = lg + r2;
      float xv;
      if (c < C_) xv = cb[(size_t)c*L_ + l];
      else if (c < CIN_) xv = pe_raw(c - C_, l);
      else xv = 0.f;
      xT[4*g + r2][c] = f2bf(xv);
    }
  }
  __syncthreads();
  f32x4 z4 = {0.f,0.f,0.f,0.f};
  f32x4 accS[8], accD[8];
  #pragma unroll
  for (int i = 0; i < 8; i++){ accS[i] = z4; accD[i] = z4; }
  #pragma unroll
  for (int k0 = 0; k0 < 96; k0 += 32){
    bh8 bfr[2];
    #pragma unroll
    for (int nt = 0; nt < 2; nt++)
      bfr[nt] = *(const bh8*)&xT[wid*32 + nt*16 + col][k0 + quad*8];
    #pragma unroll
    for (int mt = 0; mt < 4; mt++){
      bh8 af = *(const bh8*)&wsA[mt*16 + col][k0 + quad*8];
      #pragma unroll
      for (int nt = 0; nt < 2; nt++)
        accS[mt*2+nt] = __builtin_amdgcn_mfma_f32_16x16x32_bf16(af, bfr[nt], accS[mt*2+nt], 0,0,0);
    }
  }
  bh8 zz8 = {0,0,0,0,0,0,0,0};
  #pragma unroll
  for (int t = 0; t < 3; t++){
    #pragma unroll
    for (int k0 = 0; k0 < 64; k0 += 32){
      bh8 bfr[2];
      #pragma unroll
      for (int nt = 0; nt < 2; nt++){
        int l = l0 + wid*32 + nt*16 + col + t - 1;
        bfr[nt] = (l >= 0 && l < L_)
          ? *(const bh8*)&t1bf[((size_t)b*L_ + l)*64 + k0 + quad*8] : zz8;
      }
      #pragma unroll
      for (int mt = 0; mt < 4; mt++){
        bh8 af = *(const bh8*)&w1A[t][mt*16 + col][k0 + quad*8];
        #pragma unroll
        for (int nt = 0; nt < 2; nt++)
          accD[mt*2+nt] = __builtin_amdgcn_mfma_f32_16x16x32_bf16(af, bfr[nt], accD[mt*2+nt], 0,0,0);
      }
    }
  }
  #pragma unroll
  for (int mt = 0; mt < 4; mt++){
    int f0 = mt*16 + quad*4;
    float q0 = b1[f0], q1 = b1[f0+1], q2 = b1[f0+2], q3 = b1[f0+3];
    #pragma unroll
    for (int nt = 0; nt < 2; nt++){
      int l = l0 + wid*32 + nt*16 + col;
      f32x4 s = accS[mt*2+nt], d = accD[mt*2+nt];
      size_t base = ((size_t)b*C_ + f0)*L_ + l;
      x[base]        = s[0] + 0.1f*(d[0] + q0);
      x[base + L_]   = s[1] + 0.1f*(d[1] + q1);
      x[base + 2*L_] = s[2] + 0.1f*(d[2] + q2);
      x[base + 3*L_] = s[3] + 0.1f*(d[3] + q3);
    }
  }
}

// ---------------- fused 8-iteration hypernet loop, chunk-pipelined version.
// One block per b, 8 waves. Per chunk (8 channels, wave=channel):
//   [ SOBEL(c+1) -> Tbuf[(c+1)&1]  ||  GEMM(c) <- Tbuf[c&1] ] ; one barrier.
// Disjoint buffers let the scheduler interleave sobel VALU/bpermute with the
// GEMM's ds_read gather + p-loads + MFMA (separate pipes). Register-neutral
// vs r1/r2 (no xr residency -> no spills). h_t (73.7KB) aliases both T bufs.
#define CGS 520              // u16 stride between channels within a group
#define GGS 4168             // u16 stride between sobel-groups (8*520+8)
#define TBUF_ 16672          // one chunk buffer: 4*GGS u16
#define SOBEL(CN, TP) { \
      float r[8] = {nv0.x,nv0.y,nv0.z,nv0.w,nv1.x,nv1.y,nv1.z,nv1.w}; \
      if ((CN) < 7){ \
        const float* xp = xb + (size_t)(((CN)+1)*8 + wid)*L_ + lane*8; \
        nv0 = *(const float4*)xp; nv1 = *(const float4*)(xp + 4); \
      } \
      float s1 = 0.f, s2 = 0.f; \
      _Pragma("unroll") \
      for (int i = 0; i < 8; i++){ s1 += r[i]; s2 += r[i]*r[i]; } \
      _Pragma("unroll") \
      for (int m = 32; m; m >>= 1){ s1 += __shfl_xor(s1, m); s2 += __shfl_xor(s2, m); } \
      const float mean = s1 * (1.f/512.f); \
      const float rstd = rsqrtf(s2*(1.f/512.f) - mean*mean + 1e-5f); \
      float xn[8]; \
      _Pragma("unroll") \
      for (int i = 0; i < 8; i++) xn[i] = (r[i]-mean)*rstd; \
      *(uint4*)&(TP)[wid*CGS + lane*8] = pk8(xn); \
      float A[8], Bv[8]; \
      A[0] = 2.f*xn[0]+xn[1]; Bv[0] = xn[1]; \
      _Pragma("unroll") \
      for (int i = 1; i < 7; i++){ A[i] = xn[i-1]+2.f*xn[i]+xn[i+1]; Bv[i] = xn[i+1]-xn[i-1]; } \
      A[7] = xn[6]+2.f*xn[7]; Bv[7] = -xn[6]; \
      float Cv[8], Dv[8], Ev[8]; \
      _Pragma("unroll") \
      for (int i = 0; i < 8; i++){ \
        float am = shf(A[i], lmA)*wm, ap = shf(A[i], lpA)*wp; \
        Cv[i] = am + 2.f*A[i] + ap; \
        Dv[i] = ap - am; \
        float bm = shf(Bv[i], lmA)*wm, bp = shf(Bv[i], lpA)*wp; \
        Ev[i] = bm + 2.f*Bv[i] + bp; \
      } \
      float g0[8], g1[8], g2[8]; \
      _Pragma("unroll") \
      for (int i = 0; i < 8; i++){ \
        g0[i] = __sinf(shf(Cv[i], zpA)*qp - shf(Cv[i], zmA)*qm); \
        g1[i] = __sinf(shf(Dv[i], zmA)*qm + 2.f*Dv[i] + shf(Dv[i], zpA)*qp); \
        g2[i] = __sinf(shf(Ev[i], zmA)*qm + 2.f*Ev[i] + shf(Ev[i], zpA)*qp); \
      } \
      *(uint4*)&(TP)[GGS   + wid*CGS + lane*8] = pk8(g0); \
      *(uint4*)&(TP)[2*GGS + wid*CGS + lane*8] = pk8(g1); \
      *(uint4*)&(TP)[3*GGS + wid*CGS + lane*8] = pk8(g2); \
    }

__global__ __launch_bounds__(512, 1) void k_loop(float* __restrict__ x,
    const unsigned short* __restrict__ p_bf, const float* __restrict__ leak){
  const int b = blockIdx.x, tid = threadIdx.x;
  const int wid = tid >> 6, lane = tid & 63, col = lane & 15, quad = lane >> 4;
  const int yy = lane & 7, zz = lane >> 3;
  const unsigned short* pb = p_bf + (size_t)b*PT_;
  float* xb = x + (size_t)b*C_*L_;

  __shared__ __attribute__((aligned(16))) unsigned short SMEM[36864];   // 73,728 B
  unsigned short* Tb = SMEM;                                            // 2 x TBUF_
  unsigned short (*h_t)[72] = (unsigned short (*)[72])SMEM;             // alias

  const int lmA = ((yy > 0) ? lane-1 : lane)*4;  const float wm = (yy > 0) ? 1.f : 0.f;
  const int lpA = ((yy < 7) ? lane+1 : lane)*4;  const float wp = (yy < 7) ? 1.f : 0.f;
  const int zmA = ((zz > 0) ? lane-8 : lane)*4;  const float qm = (zz > 0) ? 1.f : 0.f;
  const int zpA = ((zz < 7) ? lane+8 : lane)*4;  const float qp = (zz < 7) ? 1.f : 0.f;

  const float lk = fminf(fmaxf(leak[0], 0.001f), 1000.f);
  const f32x4 z4 = {0.f,0.f,0.f,0.f};

  for (int it = 0; it < 8; ++it){
    f32x4 acc1[32];                      // [mt 0..3]=wh-part, [mt 4..7]=ws-part
    #pragma unroll
    for (int i = 0; i < 32; i++) acc1[i] = z4;

    // chunk 0 x row + sobel(0) prologue
    float4 nv0, nv1;
    { const float* xp = xb + (size_t)wid*L_ + lane*8;
      nv0 = *(const float4*)xp; nv1 = *(const float4*)(xp + 4); }
    SOBEL(0, Tb)
    __syncthreads();

    #pragma unroll 2
    for (int cc = 0; cc < 8; ++cc){
      unsigned short* Tc = Tb + (cc&1)*TBUF_;
      unsigned short* Tn = Tb + ((cc+1)&1)*TBUF_;
      if (cc < 7) SOBEL(cc+1, Tn)
      // ---- GEMM(cc): K=32 slice, phys k = quad*64 + cc*8 + j
      { bh8 bfr[4];
        #pragma unroll
        for (int nt = 0; nt < 4; nt++){
          const int n = wid*64 + nt*16 + col;
          bh8 fv;
          #pragma unroll
          for (int j = 0; j < 8; j++) fv[j] = (short)Tc[quad*GGS + j*CGS + n];
          bfr[nt] = fv;
        }
        const int kof = quad*64 + cc*8;
        #pragma unroll
        for (int mt = 0; mt < 8; mt++){
          bh8 af = (mt < 4)
            ? *(const bh8*)&pb[(size_t)(mt*16+col)*256 + kof]
            : *(const bh8*)&pb[OFF_WS + (size_t)((mt-4)*16+col)*256 + kof];
          #pragma unroll
          for (int nt = 0; nt < 4; nt++)
            acc1[mt*4+nt] = __builtin_amdgcn_mfma_f32_16x16x32_bf16(af, bfr[nt], acc1[mt*4+nt], 0,0,0);
        }
      }
      __syncthreads();
    }

    // ---- h epilogue -> h_t (writer and reader rows within the same wave)
    #pragma unroll
    for (int mt = 0; mt < 4; mt++){
      const int f0 = mt*16 + quad*4;
      const float bh0 = bf2f(pb[OFF_BH+f0]),   bh1 = bf2f(pb[OFF_BH+f0+1]);
      const float bh2 = bf2f(pb[OFF_BH+f0+2]), bh3 = bf2f(pb[OFF_BH+f0+3]);
      #pragma unroll
      for (int nt = 0; nt < 4; nt++){
        const int n = wid*64 + nt*16 + col;
        f32x4 a = acc1[mt*4+nt];
        uint2 o = { pk2(lrelu(a[0]+bh0), lrelu(a[1]+bh1)),
                    pk2(lrelu(a[2]+bh2), lrelu(a[3]+bh3)) };
        *(uint2*)&h_t[n][f0] = o;
      }
    }
    // ---- GEMM2: wl @ h (intra-wave LDS, DS pipe in-order -> no barrier)
    f32x4 acc2[16];
    #pragma unroll
    for (int i = 0; i < 16; i++) acc2[i] = z4;
    #pragma unroll
    for (int k0 = 0; k0 < 64; k0 += 32){
      bh8 hb[4];
      #pragma unroll
      for (int nt = 0; nt < 4; nt++)
        hb[nt] = *(const bh8*)&h_t[wid*64 + nt*16 + col][k0 + quad*8];
      #pragma unroll
      for (int mt = 0; mt < 4; mt++){
        bh8 al = *(const bh8*)&pb[OFF_WL + (size_t)(mt*16 + col)*64 + k0 + quad*8];
        #pragma unroll
        for (int nt = 0; nt < 4; nt++)
          acc2[mt*4+nt] = __builtin_amdgcn_mfma_f32_16x16x32_bf16(al, hb[nt], acc2[mt*4+nt], 0,0,0);
      }
    }
    // ---- x += lk * (xs + bs + 0.1*(dx + bl))
    #pragma unroll
    for (int mt = 0; mt < 4; mt++){
      const int f0 = mt*16 + quad*4;
      const float bs0 = bf2f(pb[OFF_BS+f0]),   bs1 = bf2f(pb[OFF_BS+f0+1]);
      const float bs2 = bf2f(pb[OFF_BS+f0+2]), bs3 = bf2f(pb[OFF_BS+f0+3]);
      const float bl0 = bf2f(pb[OFF_BL+f0]),   bl1 = bf2f(pb[OFF_BL+f0+1]);
      const float bl2 = bf2f(pb[OFF_BL+f0+2]), bl3 = bf2f(pb[OFF_BL+f0+3]);
      #pragma unroll
      for (int nt = 0; nt < 4; nt++){
        const int n = wid*64 + nt*16 + col;
        f32x4 xs = acc1[(mt+4)*4+nt], dx = acc2[mt*4+nt];
        size_t xi = (size_t)f0*L_ + n;
        xb[xi]        += lk*(xs[0] + bs0 + 0.1f*(dx[0] + bl0));
        xb[xi + L_]   += lk*(xs[1] + bs1 + 0.1f*(dx[1] + bl1));
        xb[xi + 2*L_] += lk*(xs[2] + bs2 + 0.1f*(dx[2] + bl2));
        xb[xi + 3*L_] += lk*(xs[3] + bs3 + 0.1f*(dx[3] + bl3));
      }
    }
    __threadfence_block();
    __syncthreads();   // x RAW + T/h_t alias boundary for next iteration
  }
}

// ---------------- conv_out1 (MFMA): t1bf = bf16(lrelu(conv3(leaky(x), out_w0)+out_b0))
__global__ __launch_bounds__(256) void k_conv_out1(const float* __restrict__ x,
    const float* __restrict__ w, const float* __restrict__ bias,
    unsigned short* __restrict__ t1bf){
  int b = blockIdx.x, l0 = blockIdx.y*128, tid = threadIdx.x;
  int wid = tid>>6, lane = tid&63, col = lane&15, quad = lane>>4;
  __shared__ __attribute__((aligned(16))) unsigned short xT[136][72];
  __shared__ __attribute__((aligned(16))) unsigned short wA[3][64][72];
  for (int i = tid; i < 64*64; i += 256){
    int m = i >> 6, cin = i & 63;
    const float* s = w + (size_t)m*192 + cin*3;
    wA[0][m][cin] = f2bf(s[0]); wA[1][m][cin] = f2bf(s[1]); wA[2][m][cin] = f2bf(s[2]);
  }
  const float* xb = x + (size_t)b*C_*L_;
  for (int i = tid; i < 64*34; i += 256){
    int c = i / 34, g = i % 34;
    int lg = l0 - 4 + 4*g;
    if (lg >= 0 && lg + 3 < L_){
      float4 f = *(const float4*)&xb[(size_t)c*L_ + lg];
      xT[4*g  ][c] = f2bf(lrelu(f.x));
      xT[4*g+1][c] = f2bf(lrelu(f.y));
      xT[4*g+2][c] = f2bf(lrelu(f.z));
      xT[4*g+3][c] = f2bf(lrelu(f.w));
    } else {
      #pragma unroll
      for (int r2 = 0; r2 < 4; r2++){
        int l = lg + r2;
        float v = (l >= 0 && l < L_) ? xb[(size_t)c*L_ + l] : 0.f;
        xT[4*g + r2][c] = f2bf(lrelu(v));
      }
    }
  }
  __syncthreads();
  f32x4 z4 = {0.f,0.f,0.f,0.f};
  f32x4 acc[8];
  #pragma unroll
  for (int i = 0; i < 8; i++) acc[i] = z4;
  #pragma unroll
  for (int t = 0; t < 3; t++){
    #pragma unroll
    for (int k0 = 0; k0 < 64; k0 += 32){
      bh8 bfr[2];
      #pragma unroll
      for (int nt = 0; nt < 2; nt++)
        bfr[nt] = *(const bh8*)&xT[wid*32 + nt*16 + col + t + 3][k0 + quad*8];
      #pragma unroll
      for (int mt = 0; mt < 4; mt++){
        bh8 af = *(const bh8*)&wA[t][mt*16 + col][k0 + quad*8];
        #pragma unroll
        for (int nt = 0; nt < 2; nt++)
          acc[mt*2+nt] = __builtin_amdgcn_mfma_f32_16x16x32_bf16(af, bfr[nt], acc[mt*2+nt], 0,0,0);
      }
    }
  }
  #pragma unroll
  for (int mt = 0; mt < 4; mt++){
    int f0 = mt*16 + quad*4;
    float q0 = bias[f0], q1 = bias[f0+1], q2 = bias[f0+2], q3 = bias[f0+3];
    #pragma unroll
    for (int nt = 0; nt < 2; nt++){
      int l = l0 + wid*32 + nt*16 + col;
      f32x4 a = acc[mt*2+nt];
      uint2 o = { pk2(lrelu(a[0]+q0), lrelu(a[1]+q1)),
                  pk2(lrelu(a[2]+q2), lrelu(a[3]+q3)) };
      *(uint2*)&t1bf[((size_t)b*L_ + l)*64 + f0] = o;
    }
  }
}

// ---------------- conv_out2 (MFMA): x += 0.1*(conv3(leaky(t1), out_w1)+out_b1)
__global__ __launch_bounds__(256) void k_conv_out2(float* __restrict__ x,
    const unsigned short* __restrict__ t1bf, const float* __restrict__ w,
    const float* __restrict__ bias){
  int b = blockIdx.x, l0 = blockIdx.y*256, tid = threadIdx.x;
  int wid = tid>>6, lane = tid&63, col = lane&15, quad = lane>>4;
  __shared__ __attribute__((aligned(16))) unsigned short wA[3][64][72];
  for (int i = tid; i < 64*64; i += 256){
    int m = i >> 6, cin = i & 63;
    const float* s = w + (size_t)m*192 + cin*3;
    wA[0][m][cin] = f2bf(s[0]); wA[1][m][cin] = f2bf(s[1]); wA[2][m][cin] = f2bf(s[2]);
  }
  __syncthreads();
  f32x4 z4 = {0.f,0.f,0.f,0.f};
  f32x4 acc[16];
  #pragma unroll
  for (int i = 0; i < 16; i++) acc[i] = z4;
  bh8 zz8 = {0,0,0,0,0,0,0,0};
  #pragma unroll
  for (int t = 0; t < 3; t++){
    #pragma unroll
    for (int k0 = 0; k0 < 64; k0 += 32){
      bh8 bfr[4];
      #pragma unroll
      for (int nt = 0; nt < 4; nt++){
        int l = l0 + wid*64 + nt*16 + col + t - 1;
        bfr[nt] = (l >= 0 && l < L_)
          ? *(const bh8*)&t1bf[((size_t)b*L_ + l)*64 + k0 + quad*8] : zz8;
      }
      #pragma unroll
      for (int mt = 0; mt < 4; mt++){
        bh8 af = *(const bh8*)&wA[t][mt*16 + col][k0 + quad*8];
        #pragma unroll
        for (int nt = 0; nt < 4; nt++)
          acc[mt*4+nt] = __builtin_amdgcn_mfma_f32_16x16x32_bf16(af, bfr[nt], acc[mt*4+nt], 0,0,0);
      }
    }
  }
  #pragma unroll
  for (int mt = 0; mt < 4; mt++){
    int f0 = mt*16 + quad*4;
    float q0 = bias[f0], q1 = bias[f0+1], q2 = bias[f0+2], q3 = bias[f0+3];
    #pragma unroll
    for (int nt = 0; nt < 4; nt++){
      int l = l0 + wid*64 + nt*16 + col;
      f32x4 a = acc[mt*4+nt];
      size_t base = ((size_t)b*C_ + f0)*L_ + l;
      x[base]        += 0.1f*(a[0] + q0);
      x[base + L_]   += 0.1f*(a[1] + q1);
      x[base + 2*L_] += 0.1f*(a[2] + q2);
      x[base + 3*L_] += 0.1f*(a[3] + q3);
    }
  }
}

// ---------------- loss: cross-entropy vs argmax(codes)
__global__ __launch_bounds__(256) void k_loss(const float* __restrict__ x,
    const float* __restrict__ codes, float* __restrict__ out){
  int b = blockIdx.x;
  int l = blockIdx.y*256 + threadIdx.x;
  const float* xb = x + (size_t)b*C_*L_ + l;
  const float* cb = codes + (size_t)b*C_*L_ + l;
  float m = -1e30f, cm = -1e30f;
  int ci = 0;
  for (int c = 0; c < C_; c++){
    float xv = xb[(size_t)c*L_];
    m = fmaxf(m, xv);
    float cv = cb[(size_t)c*L_];
    if (cv > cm){ cm = cv; ci = c; }
  }
  float s = 0.f, vi = 0.f;
  for (int c = 0; c < C_; c++){
    float xv = xb[(size_t)c*L_];
    s += expf(xv - m);
    if (c == ci) vi = xv;
  }
  float lp = vi - m - logf(s);
  __shared__ float red[256];
  red[threadIdx.x] = -lp; __syncthreads();
  for (int sft = 128; sft; sft >>= 1){
    if (threadIdx.x < sft) red[threadIdx.x] += red[threadIdx.x + sft];
    __syncthreads();
  }
  if (threadIdx.x == 0) atomicAdd(out + B_*L_, red[0] * (1.0f/131072.0f));
}

// ---------------- lat head (MFMA): two 64x64 GEMMs per (b, 256-col tile) + lat2 reduce
__global__ __launch_bounds__(256) void k_lat(const float* __restrict__ x,
    const float* __restrict__ w10, const float* __restrict__ b10,
    const float* __restrict__ w11, const float* __restrict__ b11,
    const float* __restrict__ w20, const float* __restrict__ b20,
    const float* __restrict__ w21, const float* __restrict__ b21,
    const float* __restrict__ ws2, float* __restrict__ out){
  int b = blockIdx.x, l0 = blockIdx.y*256;
  int tid = threadIdx.x;
  int wid = tid >> 6, lane = tid & 63, col = lane & 15, quad = lane >> 4;
  __shared__ __attribute__((aligned(16))) unsigned short wA[2][64][72];
  __shared__ __attribute__((aligned(16))) unsigned short Bt[256][72];

  for (int i = tid; i < 1024; i += 256){
    int arr = i >> 9, rem = i & 511, row = rem >> 3, seg = rem & 7;
    const float* src = (arr ? w11 : w10) + (size_t)row*C_ + seg*8;
    *(bh8*)&wA[arr][row][seg*8] = cvt8(*(const float4*)src, *(const float4*)(src+4));
  }
  for (int i = tid; i < 4096; i += 256){
    int c = i >> 6, seg = i & 63;
    float4 v = *(const float4*)&x[((size_t)b*C_ + c)*L_ + l0 + seg*4];
    Bt[seg*4+0][c] = f2bf(lrelu(v.x));
    Bt[seg*4+1][c] = f2bf(lrelu(v.y));
    Bt[seg*4+2][c] = f2bf(lrelu(v.z));
    Bt[seg*4+3][c] = f2bf(lrelu(v.w));
  }
  __syncthreads();
  f32x4 z4 = {0.f,0.f,0.f,0.f};
  f32x4 acc1[16];
  #pragma unroll
  for (int i = 0; i < 16; i++) acc1[i] = z4;
  #pragma unroll
  for (int k0 = 0; k0 < 64; k0 += 32){
    bh8 bfr[4];
    #pragma unroll
    for (int nt = 0; nt < 4; nt++)
      bfr[nt] = *(const bh8*)&Bt[wid*64 + nt*16 + col][k0 + quad*8];
    #pragma unroll
    for (int mt = 0; mt < 4; mt++){
      bh8 af = *(const bh8*)&wA[0][mt*16 + col][k0 + quad*8];
      #pragma unroll
      for (int nt = 0; nt < 4; nt++)
        acc1[mt*4+nt] = __builtin_amdgcn_mfma_f32_16x16x32_bf16(af, bfr[nt], acc1[mt*4+nt], 0, 0, 0);
    }
  }
  #pragma unroll
  for (int mt = 0; mt < 4; mt++){
    int f0 = mt*16 + quad*4;
    f32x4 bv = *(const f32x4*)&b10[f0];
    #pragma unroll
    for (int nt = 0; nt < 4; nt++){
      int n = wid*64 + nt*16 + col;
      f32x4 a = acc1[mt*4+nt];
      uint2 o = { pk2(lrelu(a[0]+bv[0]), lrelu(a[1]+bv[1])),
                  pk2(lrelu(a[2]+bv[2]), lrelu(a[3]+bv[3])) };
      *(uint2*)&Bt[n][f0] = o;
    }
  }
  f32x4 acc2[16];
  #pragma unroll
  for (int i = 0; i < 16; i++) acc2[i] = z4;
  #pragma unroll
  for (int k0 = 0; k0 < 64; k0 += 32){
    bh8 bfr[4];
    #pragma unroll
    for (int nt = 0; nt < 4; nt++)
      bfr[nt] = *(const bh8*)&Bt[wid*64 + nt*16 + col][k0 + quad*8];
    #pragma unroll
    for (int mt = 0; mt < 4; mt++){
      bh8 af = *(const bh8*)&wA[1][mt*16 + col][k0 + quad*8];
      #pragma unroll
      for (int nt = 0; nt < 4; nt++)
        acc2[mt*4+nt] = __builtin_amdgcn_mfma_f32_16x16x32_bf16(af, bfr[nt], acc2[mt*4+nt], 0, 0, 0);
    }
  }
  float psA[4] = {0.f,0.f,0.f,0.f}, psB[4] = {0.f,0.f,0.f,0.f};
  #pragma unroll
  for (int mt = 0; mt < 4; mt++){
    int f0 = mt*16 + quad*4;
    f32x4 b11v = *(const f32x4*)&b11[f0];
    f32x4 wsv  = *(const f32x4*)&ws2[f0];
    f32x4 w20v = *(const f32x4*)&w20[f0];
    #pragma unroll
    for (int nt = 0; nt < 4; nt++){
      int lg = l0 + wid*64 + nt*16 + col;
      size_t base = ((size_t)b*C_ + f0)*L_ + lg;
      f32x4 a = acc2[mt*4+nt];
      #pragma unroll
      for (int r = 0; r < 4; r++){
        float xv = x[base + (size_t)r*L_];
        float lat = xv + 0.1f*(a[r] + b11v[r]);
        psA[nt] += wsv[r]*lat;
        psB[nt] += w20v[r]*lrelu(lat);
      }
    }
  }
  #pragma unroll
  for (int nt = 0; nt < 4; nt++){
    psA[nt] += __shfl_xor(psA[nt], 16); psA[nt] += __shfl_xor(psA[nt], 32);
    psB[nt] += __shfl_xor(psB[nt], 16); psB[nt] += __shfl_xor(psB[nt], 32);
  }
  if (quad == 0){
    float b20s = b20[0], w21s = w21[0], b21s = b21[0];
    #pragma unroll
    for (int nt = 0; nt < 4; nt++){
      float dx2 = w21s*lrelu(psB[nt] + b20s) + b21s;
      out[(size_t)b*L_ + l0 + wid*64 + nt*16 + col] = psA[nt] + 0.1f*dx2;
    }
  }
}

extern "C" void kernel_launch(void* const* d_in, const int* in_sizes, int n_in,
                              void* d_out, int out_size, void* d_ws, size_t ws_size,
                              hipStream_t stream) {
  (void)in_sizes; (void)n_in; (void)out_size; (void)ws_size;
  const float* codes   = (const float*)d_in[0];
  const int*   y       = (const int*)  d_in[1];
  const float* fc_w    = (const float*)d_in[2];
  const float* fc_b    = (const float*)d_in[3];
  const float* in_w0   = (const float*)d_in[4];
  const float* in_b0   = (const float*)d_in[5];
  const float* in_w1   = (const float*)d_in[6];
  const float* in_b1   = (const float*)d_in[7];
  const float* in_wsp  = (const float*)d_in[8];
  const float* leak    = (const float*)d_in[9];
  const float* hyper_w = (const float*)d_in[10];
  const float* hyper_b = (const float*)d_in[11];
  const float* out_w0  = (const float*)d_in[12];
  const float* out_b0  = (const float*)d_in[13];
  const float* out_w1  = (const float*)d_in[14];
  const float* out_b1  = (const float*)d_in[15];
  const float* l1_w0   = (const float*)d_in[16];
  const float* l1_b0   = (const float*)d_in[17];
  const float* l1_w1   = (const float*)d_in[18];
  const float* l1_b1   = (const float*)d_in[19];
  const float* l2_w0   = (const float*)d_in[20];
  const float* l2_b0   = (const float*)d_in[21];
  const float* l2_w1   = (const float*)d_in[22];
  const float* l2_b1   = (const float*)d_in[23];
  const float* l2_ws   = (const float*)d_in[24];
  float* out = (float*)d_out;

  char* ws = (char*)d_ws;
  unsigned short* p_bf = (unsigned short*)(ws);              // 256*37056*2 = 18,972,672
  unsigned short* ybf  = (unsigned short*)(ws + 18972672);   // 131,072
  float* x             = (float*)(ws + 19103744);            // 33,554,432
  unsigned short* t1bf = (unsigned short*)(ws + 52658176);   // 16,777,216

  k_yemb<<<B_, 256, 0, stream>>>(fc_w, fc_b, y, ybf, out);
  k_hyper<<<PT_/64, 256, 0, stream>>>(hyper_w, hyper_b, ybf, p_bf);
  k_conv_in1<<<dim3(B_, 4), 256, 0, stream>>>(codes, in_w0, in_b0, t1bf);
  k_conv_in2<<<dim3(B_, 4), 256, 0, stream>>>(codes, in_wsp, in_w1, in_b1, t1bf, x);
  k_loop<<<B_, 512, 0, stream>>>(x, p_bf, leak);
  k_conv_out1<<<dim3(B_, 4), 256, 0, stream>>>(x, out_w0, out_b0, t1bf);
  k_conv_out2<<<dim3(B_, 2), 256, 0, stream>>>(x, t1bf, out_w1, out_b1);
  k_loss<<<dim3(B_, 2), 256, 0, stream>>>(x, codes, out);
  k_lat<<<dim3(B_, 2), 256, 0, stream>>>(x, l1_w0, l1_b0, l1_w1, l1_b1,
                                         l2_w0, l2_b0, l2_w1, l2_b1, l2_ws, out);
}

// Round 8
// 836.754 us; speedup vs baseline: 1.3444x; 1.0228x over previous
//
#include <hip/hip_runtime.h>

#define B_ 256
#define C_ 64
#define L_ 512
#define CIN_ 82
#define NFREQ_ 9
#define EMB_ 256
#define NLAB_ 10
#define PT_ 37056
#define OFF_BH 16384
#define OFF_WL 16448
#define OFF_BL 20544
#define OFF_WS 20608
#define OFF_BS 36992
#define PI_F 3.14159265358979323846f

typedef short bh8 __attribute__((ext_vector_type(8)));   // 8 bf16 (raw bits)
typedef float f32x4 __attribute__((ext_vector_type(4)));

__device__ inline float lrelu(float v){ return v > 0.f ? v : 0.2f*v; }

__device__ inline unsigned short f2bf(float f){
  unsigned u = __float_as_uint(f);
  u += 0x7FFFu + ((u >> 16) & 1u);      // RNE
  return (unsigned short)(u >> 16);
}
__device__ inline float bf2f(unsigned short u){
  return __uint_as_float((unsigned)u << 16);
}
__device__ inline unsigned pk2(float a, float b){
  return (unsigned)f2bf(a) | ((unsigned)f2bf(b) << 16);
}
__device__ inline bh8 cvt8(float4 a, float4 b){
  bh8 r;
  r[0]=(short)f2bf(a.x); r[1]=(short)f2bf(a.y); r[2]=(short)f2bf(a.z); r[3]=(short)f2bf(a.w);
  r[4]=(short)f2bf(b.x); r[5]=(short)f2bf(b.y); r[6]=(short)f2bf(b.z); r[7]=(short)f2bf(b.w);
  return r;
}
__device__ inline uint4 pk8(const float* v){
  uint4 o = { pk2(v[0],v[1]), pk2(v[2],v[3]), pk2(v[4],v[5]), pk2(v[6],v[7]) };
  return o;
}
// in-wave lane fetch via LDS-pipe permute (addr = src_lane*4)
__device__ inline float shf(float v, int a){
  return __uint_as_float((unsigned)__builtin_amdgcn_ds_bpermute(a, (int)__float_as_uint(v)));
}

// ---------------- yemb: normalize(fc_w[:,y]+fc_b) -> bf16 [b][e]; zero loss slot
__global__ __launch_bounds__(256) void k_yemb(const float* __restrict__ fc_w,
    const float* __restrict__ fc_b, const int* __restrict__ y,
    unsigned short* __restrict__ ybf, float* __restrict__ out){
  int b = blockIdx.x, e = threadIdx.x;
  int lab = y[b];
  float v = fc_w[e*NLAB_ + lab] + fc_b[e];
  __shared__ float red[256];
  red[e] = v*v; __syncthreads();
  for (int s = 128; s; s >>= 1){ if (e < s) red[e] += red[e+s]; __syncthreads(); }
  float nrm = fmaxf(sqrtf(red[0]), 1e-12f);
  ybf[(size_t)b*EMB_ + e] = f2bf(v / nrm);
  if (b == 0 && e == 0) out[B_*L_] = 0.f;
}

// ---------------- hyper (MFMA): p_bf[b][j] = bf16(yemb[b][:] . hw[j][:] + hb[j])
__global__ __launch_bounds__(256) void k_hyper(const float* __restrict__ hw,
    const float* __restrict__ hb, const unsigned short* __restrict__ ybf,
    unsigned short* __restrict__ p_bf){
  int tid = threadIdx.x;
  int wid = tid >> 6, lane = tid & 63, col = lane & 15, quad = lane >> 4;
  int j = blockIdx.x*64 + wid*16 + col;
  f32x4 acc[16];
  f32x4 z4 = {0.f,0.f,0.f,0.f};
  #pragma unroll
  for (int i = 0; i < 16; i++) acc[i] = z4;
  for (int k0 = 0; k0 < 256; k0 += 32){
    const float* hp = hw + (size_t)j*EMB_ + k0 + quad*8;
    bh8 bf = cvt8(*(const float4*)hp, *(const float4*)(hp+4));
    #pragma unroll
    for (int mt = 0; mt < 16; mt++){
      bh8 af = *(const bh8*)&ybf[(size_t)(mt*16 + col)*EMB_ + k0 + quad*8];
      acc[mt] = __builtin_amdgcn_mfma_f32_16x16x32_bf16(af, bf, acc[mt], 0, 0, 0);
    }
  }
  float hbv = hb[j];
  #pragma unroll
  for (int mt = 0; mt < 16; mt++){
    int b0 = mt*16 + quad*4;
    #pragma unroll
    for (int r = 0; r < 4; r++)
      p_bf[(size_t)(b0 + r)*PT_ + j] = f2bf(acc[mt][r] + hbv);
  }
}

// positional encoding value (raw)
__device__ inline float pe_raw(int fi, int l){
  if (fi < NFREQ_) return __sinf(PI_F / (float)(1 << fi) * (float)l);
  return __cosf(PI_F / (float)(1 << (fi - NFREQ_)) * (float)l);
}

// ---------------- conv_in1 (MFMA): t1bf[b][l][m] = bf16(lrelu(conv3(leaky(xcat), in_w0)+in_b0))
__global__ __launch_bounds__(256) void k_conv_in1(const float* __restrict__ codes,
    const float* __restrict__ w0, const float* __restrict__ b0,
    unsigned short* __restrict__ t1bf){
  int b = blockIdx.x, l0 = blockIdx.y*128, tid = threadIdx.x;
  int wid = tid>>6, lane = tid&63, col = lane&15, quad = lane>>4;
  __shared__ __attribute__((aligned(16))) unsigned short xT[136][96];
  __shared__ __attribute__((aligned(16))) unsigned short wA[3][64][96];
  for (int i = tid; i < 64*96; i += 256){
    int m = i / 96, cin = i % 96;
    if (cin < CIN_){
      const float* s = w0 + (size_t)m*(CIN_*3) + cin*3;
      wA[0][m][cin] = f2bf(s[0]); wA[1][m][cin] = f2bf(s[1]); wA[2][m][cin] = f2bf(s[2]);
    } else { wA[0][m][cin] = 0; wA[1][m][cin] = 0; wA[2][m][cin] = 0; }
  }
  const float* cb = codes + (size_t)b*C_*L_;
  for (int i = tid; i < 96*34; i += 256){
    int c = i / 34, g = i % 34;
    int lg = l0 - 4 + 4*g;
    #pragma unroll
    for (int r2 = 0; r2 < 4; r2++){
      int l = lg + r2;
      float xv = 0.f;
      if (l >= 0 && l < L_){
        if (c < C_) xv = cb[(size_t)c*L_ + l];
        else if (c < CIN_) xv = pe_raw(c - C_, l);
      }
      xT[4*g + r2][c] = f2bf(lrelu(xv));
    }
  }
  __syncthreads();
  f32x4 z4 = {0.f,0.f,0.f,0.f};
  f32x4 acc[8];
  #pragma unroll
  for (int i = 0; i < 8; i++) acc[i] = z4;
  #pragma unroll
  for (int t = 0; t < 3; t++){
    #pragma unroll
    for (int k0 = 0; k0 < 96; k0 += 32){
      bh8 bfr[2];
      #pragma unroll
      for (int nt = 0; nt < 2; nt++)
        bfr[nt] = *(const bh8*)&xT[wid*32 + nt*16 + col + t + 3][k0 + quad*8];
      #pragma unroll
      for (int mt = 0; mt < 4; mt++){
        bh8 af = *(const bh8*)&wA[t][mt*16 + col][k0 + quad*8];
        #pragma unroll
        for (int nt = 0; nt < 2; nt++)
          acc[mt*2+nt] = __builtin_amdgcn_mfma_f32_16x16x32_bf16(af, bfr[nt], acc[mt*2+nt], 0,0,0);
      }
    }
  }
  #pragma unroll
  for (int mt = 0; mt < 4; mt++){
    int f0 = mt*16 + quad*4;
    float q0 = b0[f0], q1 = b0[f0+1], q2 = b0[f0+2], q3 = b0[f0+3];
    #pragma unroll
    for (int nt = 0; nt < 2; nt++){
      int l = l0 + wid*32 + nt*16 + col;
      f32x4 a = acc[mt*2+nt];
      uint2 o = { pk2(lrelu(a[0]+q0), lrelu(a[1]+q1)),
                  pk2(lrelu(a[2]+q2), lrelu(a[3]+q3)) };
      *(uint2*)&t1bf[((size_t)b*L_ + l)*64 + f0] = o;
    }
  }
}

// ---------------- conv_in2 (MFMA): x = conv1x1(xcat, in_ws) + 0.1*(conv3(leaky(t1), in_w1)+in_b1)
__global__ __launch_bounds__(256) void k_conv_in2(const float* __restrict__ codes,
    const float* __restrict__ wsp, const float* __restrict__ w1, const float* __restrict__ b1,
    const unsigned short* __restrict__ t1bf, float* __restrict__ x){
  int b = blockIdx.x, l0 = blockIdx.y*128, tid = threadIdx.x;
  int wid = tid>>6, lane = tid&63, col = lane&15, quad = lane>>4;
  __shared__ __attribute__((aligned(16))) unsigned short xT[128][96];
  __shared__ __attribute__((aligned(16))) unsigned short wsA[64][96];
  __shared__ __attribute__((aligned(16))) unsigned short w1A[3][64][72];
  for (int i = tid; i < 64*96; i += 256){
    int m = i / 96, cin = i % 96;
    wsA[m][cin] = (cin < CIN_) ? f2bf(wsp[(size_t)m*CIN_ + cin]) : (unsigned short)0;
  }
  for (int i = tid; i < 64*64; i += 256){
    int m = i >> 6, cin = i & 63;
    const float* s = w1 + (size_t)m*192 + cin*3;
    w1A[0][m][cin] = f2bf(s[0]); w1A[1][m][cin] = f2bf(s[1]); w1A[2][m][cin] = f2bf(s[2]);
  }
  const float* cb = codes + (size_t)b*C_*L_;
  for (int i = tid; i < 96*32; i += 256){
    int c = i / 32, g = i % 32;
    int lg = l0 + 4*g;
    #pragma unroll
    for (int r2 = 0; r2 < 4; r2++){
      int l = lg + r2;
      float xv;
      if (c < C_) xv = cb[(size_t)c*L_ + l];
      else if (c < CIN_) xv = pe_raw(c - C_, l);
      else xv = 0.f;
      xT[4*g + r2][c] = f2bf(xv);
    }
  }
  __syncthreads();
  f32x4 z4 = {0.f,0.f,0.f,0.f};
  f32x4 accS[8], accD[8];
  #pragma unroll
  for (int i = 0; i < 8; i++){ accS[i] = z4; accD[i] = z4; }
  #pragma unroll
  for (int k0 = 0; k0 < 96; k0 += 32){
    bh8 bfr[2];
    #pragma unroll
    for (int nt = 0; nt < 2; nt++)
      bfr[nt] = *(const bh8*)&xT[wid*32 + nt*16 + col][k0 + quad*8];
    #pragma unroll
    for (int mt = 0; mt < 4; mt++){
      bh8 af = *(const bh8*)&wsA[mt*16 + col][k0 + quad*8];
      #pragma unroll
      for (int nt = 0; nt < 2; nt++)
        accS[mt*2+nt] = __builtin_amdgcn_mfma_f32_16x16x32_bf16(af, bfr[nt], accS[mt*2+nt], 0,0,0);
    }
  }
  bh8 zz8 = {0,0,0,0,0,0,0,0};
  #pragma unroll
  for (int t = 0; t < 3; t++){
    #pragma unroll
    for (int k0 = 0; k0 < 64; k0 += 32){
      bh8 bfr[2];
      #pragma unroll
      for (int nt = 0; nt < 2; nt++){
        int l = l0 + wid*32 + nt*16 + col + t - 1;
        bfr[nt] = (l >= 0 && l < L_)
          ? *(const bh8*)&t1bf[((size_t)b*L_ + l)*64 + k0 + quad*8] : zz8;
      }
      #pragma unroll
      for (int mt = 0; mt < 4; mt++){
        bh8 af = *(const bh8*)&w1A[t][mt*16 + col][k0 + quad*8];
        #pragma unroll
        for (int nt = 0; nt < 2; nt++)
          accD[mt*2+nt] = __builtin_amdgcn_mfma_f32_16x16x32_bf16(af, bfr[nt], accD[mt*2+nt], 0,0,0);
      }
    }
  }
  #pragma unroll
  for (int mt = 0; mt < 4; mt++){
    int f0 = mt*16 + quad*4;
    float q0 = b1[f0], q1 = b1[f0+1], q2 = b1[f0+2], q3 = b1[f0+3];
    #pragma unroll
    for (int nt = 0; nt < 2; nt++){
      int l = l0 + wid*32 + nt*16 + col;
      f32x4 s = accS[mt*2+nt], d = accD[mt*2+nt];
      size_t base = ((size_t)b*C_ + f0)*L_ + l;
      x[base]        = s[0] + 0.1f*(d[0] + q0);
      x[base + L_]   = s[1] + 0.1f*(d[1] + q1);
      x[base + 2*L_] = s[2] + 0.1f*(d[2] + q2);
      x[base + 3*L_] = s[3] + 0.1f*(d[3] + q3);
    }
  }
}

// ---------------- fused 8-iteration hypernet loop, deferred-update version.
// One block per b, 8 waves. r6's chunk pipeline retained. NEW: the x update is
// NOT applied via a global RMW each iteration; the epilogue (iters 0..6) writes
// the bf16 update U[c][s] to LDS, and the NEXT iteration's phase A adds U to the
// freshly-loaded x row and writes x_new back (fire-and-forget, same thread reads
// it next iter). Eliminates the epilogue's 33.5MB/iter L2-missing x re-read.
// Iter 7 keeps the original global RMW (final x), fenced (cross-wave RAW).
#define CGS 520              // u16 stride between channels within a group
#define GGS 4168             // u16 stride between sobel-groups (8*520+8)
#define TBUF_ 16672          // one chunk buffer: 4*GGS u16
#define UST 520              // U row stride in u16 (512 + 8 pad)
#define SOBEL(CN, TP) { \
      float r[8] = {nv0.x,nv0.y,nv0.z,nv0.w,nv1.x,nv1.y,nv1.z,nv1.w}; \
      if (aplu){ \
        const uint4 uv = *(const uint4*)&Ub[(size_t)((CN)*8 + wid)*UST + lane*8]; \
        r[0] += bf2f((unsigned short)(uv.x & 0xffffu)); r[1] += bf2f((unsigned short)(uv.x >> 16)); \
        r[2] += bf2f((unsigned short)(uv.y & 0xffffu)); r[3] += bf2f((unsigned short)(uv.y >> 16)); \
        r[4] += bf2f((unsigned short)(uv.z & 0xffffu)); r[5] += bf2f((unsigned short)(uv.z >> 16)); \
        r[6] += bf2f((unsigned short)(uv.w & 0xffffu)); r[7] += bf2f((unsigned short)(uv.w >> 16)); \
        float* xw = xb + (size_t)((CN)*8 + wid)*L_ + lane*8; \
        float4 w0 = {r[0],r[1],r[2],r[3]}, w1 = {r[4],r[5],r[6],r[7]}; \
        *(float4*)xw = w0; *(float4*)(xw + 4) = w1; \
      } \
      if ((CN) < 7){ \
        const float* xp = xb + (size_t)(((CN)+1)*8 + wid)*L_ + lane*8; \
        nv0 = *(const float4*)xp; nv1 = *(const float4*)(xp + 4); \
      } \
      float s1 = 0.f, s2 = 0.f; \
      _Pragma("unroll") \
      for (int i = 0; i < 8; i++){ s1 += r[i]; s2 += r[i]*r[i]; } \
      _Pragma("unroll") \
      for (int m = 32; m; m >>= 1){ s1 += __shfl_xor(s1, m); s2 += __shfl_xor(s2, m); } \
      const float mean = s1 * (1.f/512.f); \
      const float rstd = rsqrtf(s2*(1.f/512.f) - mean*mean + 1e-5f); \
      float xn[8]; \
      _Pragma("unroll") \
      for (int i = 0; i < 8; i++) xn[i] = (r[i]-mean)*rstd; \
      *(uint4*)&(TP)[wid*CGS + lane*8] = pk8(xn); \
      float A[8], Bv[8]; \
      A[0] = 2.f*xn[0]+xn[1]; Bv[0] = xn[1]; \
      _Pragma("unroll") \
      for (int i = 1; i < 7; i++){ A[i] = xn[i-1]+2.f*xn[i]+xn[i+1]; Bv[i] = xn[i+1]-xn[i-1]; } \
      A[7] = xn[6]+2.f*xn[7]; Bv[7] = -xn[6]; \
      float Cv[8], Dv[8], Ev[8]; \
      _Pragma("unroll") \
      for (int i = 0; i < 8; i++){ \
        float am = shf(A[i], lmA)*wm, ap = shf(A[i], lpA)*wp; \
        Cv[i] = am + 2.f*A[i] + ap; \
        Dv[i] = ap - am; \
        float bm = shf(Bv[i], lmA)*wm, bp = shf(Bv[i], lpA)*wp; \
        Ev[i] = bm + 2.f*Bv[i] + bp; \
      } \
      float g0[8], g1[8], g2[8]; \
      _Pragma("unroll") \
      for (int i = 0; i < 8; i++){ \
        g0[i] = __sinf(shf(Cv[i], zpA)*qp - shf(Cv[i], zmA)*qm); \
        g1[i] = __sinf(shf(Dv[i], zmA)*qm + 2.f*Dv[i] + shf(Dv[i], zpA)*qp); \
        g2[i] = __sinf(shf(Ev[i], zmA)*qm + 2.f*Ev[i] + shf(Ev[i], zpA)*qp); \
      } \
      *(uint4*)&(TP)[GGS   + wid*CGS + lane*8] = pk8(g0); \
      *(uint4*)&(TP)[2*GGS + wid*CGS + lane*8] = pk8(g1); \
      *(uint4*)&(TP)[3*GGS + wid*CGS + lane*8] = pk8(g2); \
    }

__global__ __launch_bounds__(512, 1) void k_loop(float* __restrict__ x,
    const unsigned short* __restrict__ p_bf, const float* __restrict__ leak){
  const int b = blockIdx.x, tid = threadIdx.x;
  const int wid = tid >> 6, lane = tid & 63, col = lane & 15, quad = lane >> 4;
  const int yy = lane & 7, zz = lane >> 3;
  const unsigned short* pb = p_bf + (size_t)b*PT_;
  float* xb = x + (size_t)b*C_*L_;

  // [0, 36864) u16: T double-buffer (2 x TBUF_) / h_t[512][72] alias
  // [36864, 36864+64*UST) u16: U deferred-update buffer (bf16 [64][UST])
  __shared__ __attribute__((aligned(16))) unsigned short SMEM[36864 + 64*UST]; // 140,288 B
  unsigned short* Tb = SMEM;
  unsigned short (*h_t)[72] = (unsigned short (*)[72])SMEM;
  unsigned short* Ub = SMEM + 36864;

  const int lmA = ((yy > 0) ? lane-1 : lane)*4;  const float wm = (yy > 0) ? 1.f : 0.f;
  const int lpA = ((yy < 7) ? lane+1 : lane)*4;  const float wp = (yy < 7) ? 1.f : 0.f;
  const int zmA = ((zz > 0) ? lane-8 : lane)*4;  const float qm = (zz > 0) ? 1.f : 0.f;
  const int zpA = ((zz < 7) ? lane+8 : lane)*4;  const float qp = (zz < 7) ? 1.f : 0.f;

  const float lk = fminf(fmaxf(leak[0], 0.001f), 1000.f);
  const f32x4 z4 = {0.f,0.f,0.f,0.f};

  for (int it = 0; it < 8; ++it){
    const bool aplu = (it > 0);
    f32x4 acc1[32];                      // [mt 0..3]=wh-part, [mt 4..7]=ws-part
    #pragma unroll
    for (int i = 0; i < 32; i++) acc1[i] = z4;

    // chunk 0 x row + sobel(0) prologue
    float4 nv0, nv1;
    { const float* xp = xb + (size_t)wid*L_ + lane*8;
      nv0 = *(const float4*)xp; nv1 = *(const float4*)(xp + 4); }
    SOBEL(0, Tb)
    __syncthreads();

    #pragma unroll 2
    for (int cc = 0; cc < 8; ++cc){
      unsigned short* Tc = Tb + (cc&1)*TBUF_;
      unsigned short* Tn = Tb + ((cc+1)&1)*TBUF_;
      if (cc < 7) SOBEL(cc+1, Tn)
      // ---- GEMM(cc): K=32 slice, phys k = quad*64 + cc*8 + j
      { bh8 bfr[4];
        #pragma unroll
        for (int nt = 0; nt < 4; nt++){
          const int n = wid*64 + nt*16 + col;
          bh8 fv;
          #pragma unroll
          for (int j = 0; j < 8; j++) fv[j] = (short)Tc[quad*GGS + j*CGS + n];
          bfr[nt] = fv;
        }
        const int kof = quad*64 + cc*8;
        #pragma unroll
        for (int mt = 0; mt < 8; mt++){
          bh8 af = (mt < 4)
            ? *(const bh8*)&pb[(size_t)(mt*16+col)*256 + kof]
            : *(const bh8*)&pb[OFF_WS + (size_t)((mt-4)*16+col)*256 + kof];
          #pragma unroll
          for (int nt = 0; nt < 4; nt++)
            acc1[mt*4+nt] = __builtin_amdgcn_mfma_f32_16x16x32_bf16(af, bfr[nt], acc1[mt*4+nt], 0,0,0);
        }
      }
      __syncthreads();
    }

    // ---- h epilogue -> h_t (writer and reader rows within the same wave)
    #pragma unroll
    for (int mt = 0; mt < 4; mt++){
      const int f0 = mt*16 + quad*4;
      const float bh0 = bf2f(pb[OFF_BH+f0]),   bh1 = bf2f(pb[OFF_BH+f0+1]);
      const float bh2 = bf2f(pb[OFF_BH+f0+2]), bh3 = bf2f(pb[OFF_BH+f0+3]);
      #pragma unroll
      for (int nt = 0; nt < 4; nt++){
        const int n = wid*64 + nt*16 + col;
        f32x4 a = acc1[mt*4+nt];
        uint2 o = { pk2(lrelu(a[0]+bh0), lrelu(a[1]+bh1)),
                    pk2(lrelu(a[2]+bh2), lrelu(a[3]+bh3)) };
        *(uint2*)&h_t[n][f0] = o;
      }
    }
    // ---- GEMM2: wl @ h (intra-wave LDS, DS pipe in-order -> no barrier)
    f32x4 acc2[16];
    #pragma unroll
    for (int i = 0; i < 16; i++) acc2[i] = z4;
    #pragma unroll
    for (int k0 = 0; k0 < 64; k0 += 32){
      bh8 hb[4];
      #pragma unroll
      for (int nt = 0; nt < 4; nt++)
        hb[nt] = *(const bh8*)&h_t[wid*64 + nt*16 + col][k0 + quad*8];
      #pragma unroll
      for (int mt = 0; mt < 4; mt++){
        bh8 al = *(const bh8*)&pb[OFF_WL + (size_t)(mt*16 + col)*64 + k0 + quad*8];
        #pragma unroll
        for (int nt = 0; nt < 4; nt++)
          acc2[mt*4+nt] = __builtin_amdgcn_mfma_f32_16x16x32_bf16(al, hb[nt], acc2[mt*4+nt], 0,0,0);
      }
    }

    if (it < 7){
      // ---- deferred update: U[c][s] = bf16(lk*(xs + bs + 0.1*(dx + bl))) in LDS
      #pragma unroll
      for (int mt = 0; mt < 4; mt++){
        const int f0 = mt*16 + quad*4;
        const float bs0 = bf2f(pb[OFF_BS+f0]),   bs1 = bf2f(pb[OFF_BS+f0+1]);
        const float bs2 = bf2f(pb[OFF_BS+f0+2]), bs3 = bf2f(pb[OFF_BS+f0+3]);
        const float bl0 = bf2f(pb[OFF_BL+f0]),   bl1 = bf2f(pb[OFF_BL+f0+1]);
        const float bl2 = bf2f(pb[OFF_BL+f0+2]), bl3 = bf2f(pb[OFF_BL+f0+3]);
        #pragma unroll
        for (int nt = 0; nt < 4; nt++){
          const int n = wid*64 + nt*16 + col;
          f32x4 xs = acc1[(mt+4)*4+nt], dx = acc2[mt*4+nt];
          Ub[(size_t)(f0+0)*UST + n] = f2bf(lk*(xs[0] + bs0 + 0.1f*(dx[0] + bl0)));
          Ub[(size_t)(f0+1)*UST + n] = f2bf(lk*(xs[1] + bs1 + 0.1f*(dx[1] + bl1)));
          Ub[(size_t)(f0+2)*UST + n] = f2bf(lk*(xs[2] + bs2 + 0.1f*(dx[2] + bl2)));
          Ub[(size_t)(f0+3)*UST + n] = f2bf(lk*(xs[3] + bs3 + 0.1f*(dx[3] + bl3)));
        }
      }
    } else {
      // ---- final iteration: apply update via global RMW (x was last written by
      // phase A cross-wave -> fence + barrier before reading)
      __threadfence_block();
      __syncthreads();
      #pragma unroll
      for (int mt = 0; mt < 4; mt++){
        const int f0 = mt*16 + quad*4;
        const float bs0 = bf2f(pb[OFF_BS+f0]),   bs1 = bf2f(pb[OFF_BS+f0+1]);
        const float bs2 = bf2f(pb[OFF_BS+f0+2]), bs3 = bf2f(pb[OFF_BS+f0+3]);
        const float bl0 = bf2f(pb[OFF_BL+f0]),   bl1 = bf2f(pb[OFF_BL+f0+1]);
        const float bl2 = bf2f(pb[OFF_BL+f0+2]), bl3 = bf2f(pb[OFF_BL+f0+3]);
        #pragma unroll
        for (int nt = 0; nt < 4; nt++){
          const int n = wid*64 + nt*16 + col;
          f32x4 xs = acc1[(mt+4)*4+nt], dx = acc2[mt*4+nt];
          size_t xi = (size_t)f0*L_ + n;
          xb[xi]        += lk*(xs[0] + bs0 + 0.1f*(dx[0] + bl0));
          xb[xi + L_]   += lk*(xs[1] + bs1 + 0.1f*(dx[1] + bl1));
          xb[xi + 2*L_] += lk*(xs[2] + bs2 + 0.1f*(dx[2] + bl2));
          xb[xi + 3*L_] += lk*(xs[3] + bs3 + 0.1f*(dx[3] + bl3));
        }
      }
    }
    __threadfence_block();
    __syncthreads();   // U visible to next phase A + T/h_t alias boundary
  }
}

// ---------------- conv_out1 (MFMA): t1bf = bf16(lrelu(conv3(leaky(x), out_w0)+out_b0))
__global__ __launch_bounds__(256) void k_conv_out1(const float* __restrict__ x,
    const float* __restrict__ w, const float* __restrict__ bias,
    unsigned short* __restrict__ t1bf){
  int b = blockIdx.x, l0 = blockIdx.y*128, tid = threadIdx.x;
  int wid = tid>>6, lane = tid&63, col = lane&15, quad = lane>>4;
  __shared__ __attribute__((aligned(16))) unsigned short xT[136][72];
  __shared__ __attribute__((aligned(16))) unsigned short wA[3][64][72];
  for (int i = tid; i < 64*64; i += 256){
    int m = i >> 6, cin = i & 63;
    const float* s = w + (size_t)m*192 + cin*3;
    wA[0][m][cin] = f2bf(s[0]); wA[1][m][cin] = f2bf(s[1]); wA[2][m][cin] = f2bf(s[2]);
  }
  const float* xb = x + (size_t)b*C_*L_;
  for (int i = tid; i < 64*34; i += 256){
    int c = i / 34, g = i % 34;
    int lg = l0 - 4 + 4*g;
    if (lg >= 0 && lg + 3 < L_){
      float4 f = *(const float4*)&xb[(size_t)c*L_ + lg];
      xT[4*g  ][c] = f2bf(lrelu(f.x));
      xT[4*g+1][c] = f2bf(lrelu(f.y));
      xT[4*g+2][c] = f2bf(lrelu(f.z));
      xT[4*g+3][c] = f2bf(lrelu(f.w));
    } else {
      #pragma unroll
      for (int r2 = 0; r2 < 4; r2++){
        int l = lg + r2;
        float v = (l >= 0 && l < L_) ? xb[(size_t)c*L_ + l] : 0.f;
        xT[4*g + r2][c] = f2bf(lrelu(v));
      }
    }
  }
  __syncthreads();
  f32x4 z4 = {0.f,0.f,0.f,0.f};
  f32x4 acc[8];
  #pragma unroll
  for (int i = 0; i < 8; i++) acc[i] = z4;
  #pragma unroll
  for (int t = 0; t < 3; t++){
    #pragma unroll
    for (int k0 = 0; k0 < 64; k0 += 32){
      bh8 bfr[2];
      #pragma unroll
      for (int nt = 0; nt < 2; nt++)
        bfr[nt] = *(const bh8*)&xT[wid*32 + nt*16 + col + t + 3][k0 + quad*8];
      #pragma unroll
      for (int mt = 0; mt < 4; mt++){
        bh8 af = *(const bh8*)&wA[t][mt*16 + col][k0 + quad*8];
        #pragma unroll
        for (int nt = 0; nt < 2; nt++)
          acc[mt*2+nt] = __builtin_amdgcn_mfma_f32_16x16x32_bf16(af, bfr[nt], acc[mt*2+nt], 0,0,0);
      }
    }
  }
  #pragma unroll
  for (int mt = 0; mt < 4; mt++){
    int f0 = mt*16 + quad*4;
    float q0 = bias[f0], q1 = bias[f0+1], q2 = bias[f0+2], q3 = bias[f0+3];
    #pragma unroll
    for (int nt = 0; nt < 2; nt++){
      int l = l0 + wid*32 + nt*16 + col;
      f32x4 a = acc[mt*2+nt];
      uint2 o = { pk2(lrelu(a[0]+q0), lrelu(a[1]+q1)),
                  pk2(lrelu(a[2]+q2), lrelu(a[3]+q3)) };
      *(uint2*)&t1bf[((size_t)b*L_ + l)*64 + f0] = o;
    }
  }
}

// ---------------- conv_out2 (MFMA): x += 0.1*(conv3(leaky(t1), out_w1)+out_b1)
__global__ __launch_bounds__(256) void k_conv_out2(float* __restrict__ x,
    const unsigned short* __restrict__ t1bf, const float* __restrict__ w,
    const float* __restrict__ bias){
  int b = blockIdx.x, l0 = blockIdx.y*256, tid = threadIdx.x;
  int wid = tid>>6, lane = tid&63, col = lane&15, quad = lane>>4;
  __shared__ __attribute__((aligned(16))) unsigned short wA[3][64][72];
  for (int i = tid; i < 64*64; i += 256){
    int m = i >> 6, cin = i & 63;
    const float* s = w + (size_t)m*192 + cin*3;
    wA[0][m][cin] = f2bf(s[0]); wA[1][m][cin] = f2bf(s[1]); wA[2][m][cin] = f2bf(s[2]);
  }
  __syncthreads();
  f32x4 z4 = {0.f,0.f,0.f,0.f};
  f32x4 acc[16];
  #pragma unroll
  for (int i = 0; i < 16; i++) acc[i] = z4;
  bh8 zz8 = {0,0,0,0,0,0,0,0};
  #pragma unroll
  for (int t = 0; t < 3; t++){
    #pragma unroll
    for (int k0 = 0; k0 < 64; k0 += 32){
      bh8 bfr[4];
      #pragma unroll
      for (int nt = 0; nt < 4; nt++){
        int l = l0 + wid*64 + nt*16 + col + t - 1;
        bfr[nt] = (l >= 0 && l < L_)
          ? *(const bh8*)&t1bf[((size_t)b*L_ + l)*64 + k0 + quad*8] : zz8;
      }
      #pragma unroll
      for (int mt = 0; mt < 4; mt++){
        bh8 af = *(const bh8*)&wA[t][mt*16 + col][k0 + quad*8];
        #pragma unroll
        for (int nt = 0; nt < 4; nt++)
          acc[mt*4+nt] = __builtin_amdgcn_mfma_f32_16x16x32_bf16(af, bfr[nt], acc[mt*4+nt], 0,0,0);
      }
    }
  }
  #pragma unroll
  for (int mt = 0; mt < 4; mt++){
    int f0 = mt*16 + quad*4;
    float q0 = bias[f0], q1 = bias[f0+1], q2 = bias[f0+2], q3 = bias[f0+3];
    #pragma unroll
    for (int nt = 0; nt < 4; nt++){
      int l = l0 + wid*64 + nt*16 + col;
      f32x4 a = acc[mt*4+nt];
      size_t base = ((size_t)b*C_ + f0)*L_ + l;
      x[base]        += 0.1f*(a[0] + q0);
      x[base + L_]   += 0.1f*(a[1] + q1);
      x[base + 2*L_] += 0.1f*(a[2] + q2);
      x[base + 3*L_] += 0.1f*(a[3] + q3);
    }
  }
}

// ---------------- loss: cross-entropy vs argmax(codes)
__global__ __launch_bounds__(256) void k_loss(const float* __restrict__ x,
    const float* __restrict__ codes, float* __restrict__ out){
  int b = blockIdx.x;
  int l = blockIdx.y*256 + threadIdx.x;
  const float* xb = x + (size_t)b*C_*L_ + l;
  const float* cb = codes + (size_t)b*C_*L_ + l;
  float m = -1e30f, cm = -1e30f;
  int ci = 0;
  for (int c = 0; c < C_; c++){
    float xv = xb[(size_t)c*L_];
    m = fmaxf(m, xv);
    float cv = cb[(size_t)c*L_];
    if (cv > cm){ cm = cv; ci = c; }
  }
  float s = 0.f, vi = 0.f;
  for (int c = 0; c < C_; c++){
    float xv = xb[(size_t)c*L_];
    s += expf(xv - m);
    if (c == ci) vi = xv;
  }
  float lp = vi - m - logf(s);
  __shared__ float red[256];
  red[threadIdx.x] = -lp; __syncthreads();
  for (int sft = 128; sft; sft >>= 1){
    if (threadIdx.x < sft) red[threadIdx.x] += red[threadIdx.x + sft];
    __syncthreads();
  }
  if (threadIdx.x == 0) atomicAdd(out + B_*L_, red[0] * (1.0f/131072.0f));
}

// ---------------- lat head (MFMA): two 64x64 GEMMs per (b, 256-col tile) + lat2 reduce
__global__ __launch_bounds__(256) void k_lat(const float* __restrict__ x,
    const float* __restrict__ w10, const float* __restrict__ b10,
    const float* __restrict__ w11, const float* __restrict__ b11,
    const float* __restrict__ w20, const float* __restrict__ b20,
    const float* __restrict__ w21, const float* __restrict__ b21,
    const float* __restrict__ ws2, float* __restrict__ out){
  int b = blockIdx.x, l0 = blockIdx.y*256;
  int tid = threadIdx.x;
  int wid = tid >> 6, lane = tid & 63, col = lane & 15, quad = lane >> 4;
  __shared__ __attribute__((aligned(16))) unsigned short wA[2][64][72];
  __shared__ __attribute__((aligned(16))) unsigned short Bt[256][72];

  for (int i = tid; i < 1024; i += 256){
    int arr = i >> 9, rem = i & 511, row = rem >> 3, seg = rem & 7;
    const float* src = (arr ? w11 : w10) + (size_t)row*C_ + seg*8;
    *(bh8*)&wA[arr][row][seg*8] = cvt8(*(const float4*)src, *(const float4*)(src+4));
  }
  for (int i = tid; i < 4096; i += 256){
    int c = i >> 6, seg = i & 63;
    float4 v = *(const float4*)&x[((size_t)b*C_ + c)*L_ + l0 + seg*4];
    Bt[seg*4+0][c] = f2bf(lrelu(v.x));
    Bt[seg*4+1][c] = f2bf(lrelu(v.y));
    Bt[seg*4+2][c] = f2bf(lrelu(v.z));
    Bt[seg*4+3][c] = f2bf(lrelu(v.w));
  }
  __syncthreads();
  f32x4 z4 = {0.f,0.f,0.f,0.f};
  f32x4 acc1[16];
  #pragma unroll
  for (int i = 0; i < 16; i++) acc1[i] = z4;
  #pragma unroll
  for (int k0 = 0; k0 < 64; k0 += 32){
    bh8 bfr[4];
    #pragma unroll
    for (int nt = 0; nt < 4; nt++)
      bfr[nt] = *(const bh8*)&Bt[wid*64 + nt*16 + col][k0 + quad*8];
    #pragma unroll
    for (int mt = 0; mt < 4; mt++){
      bh8 af = *(const bh8*)&wA[0][mt*16 + col][k0 + quad*8];
      #pragma unroll
      for (int nt = 0; nt < 4; nt++)
        acc1[mt*4+nt] = __builtin_amdgcn_mfma_f32_16x16x32_bf16(af, bfr[nt], acc1[mt*4+nt], 0, 0, 0);
    }
  }
  #pragma unroll
  for (int mt = 0; mt < 4; mt++){
    int f0 = mt*16 + quad*4;
    f32x4 bv = *(const f32x4*)&b10[f0];
    #pragma unroll
    for (int nt = 0; nt < 4; nt++){
      int n = wid*64 + nt*16 + col;
      f32x4 a = acc1[mt*4+nt];
      uint2 o = { pk2(lrelu(a[0]+bv[0]), lrelu(a[1]+bv[1])),
                  pk2(lrelu(a[2]+bv[2]), lrelu(a[3]+bv[3])) };
      *(uint2*)&Bt[n][f0] = o;
    }
  }
  f32x4 acc2[16];
  #pragma unroll
  for (int i = 0; i < 16; i++) acc2[i] = z4;
  #pragma unroll
  for (int k0 = 0; k0 < 64; k0 += 32){
    bh8 bfr[4];
    #pragma unroll
    for (int nt = 0; nt < 4; nt++)
      bfr[nt] = *(const bh8*)&Bt[wid*64 + nt*16 + col][k0 + quad*8];
    #pragma unroll
    for (int mt = 0; mt < 4; mt++){
      bh8 af = *(const bh8*)&wA[1][mt*16 + col][k0 + quad*8];
      #pragma unroll
      for (int nt = 0; nt < 4; nt++)
        acc2[mt*4+nt] = __builtin_amdgcn_mfma_f32_16x16x32_bf16(af, bfr[nt], acc2[mt*4+nt], 0, 0, 0);
    }
  }
  float psA[4] = {0.f,0.f,0.f,0.f}, psB[4] = {0.f,0.f,0.f,0.f};
  #pragma unroll
  for (int mt = 0; mt < 4; mt++){
    int f0 = mt*16 + quad*4;
    f32x4 b11v = *(const f32x4*)&b11[f0];
    f32x4 wsv  = *(const f32x4*)&ws2[f0];
    f32x4 w20v = *(const f32x4*)&w20[f0];
    #pragma unroll
    for (int nt = 0; nt < 4; nt++){
      int lg = l0 + wid*64 + nt*16 + col;
      size_t base = ((size_t)b*C_ + f0)*L_ + lg;
      f32x4 a = acc2[mt*4+nt];
      #pragma unroll
      for (int r = 0; r < 4; r++){
        float xv = x[base + (size_t)r*L_];
        float lat = xv + 0.1f*(a[r] + b11v[r]);
        psA[nt] += wsv[r]*lat;
        psB[nt] += w20v[r]*lrelu(lat);
      }
    }
  }
  #pragma unroll
  for (int nt = 0; nt < 4; nt++){
    psA[nt] += __shfl_xor(psA[nt], 16); psA[nt] += __shfl_xor(psA[nt], 32);
    psB[nt] += __shfl_xor(psB[nt], 16); psB[nt] += __shfl_xor(psB[nt], 32);
  }
  if (quad == 0){
    float b20s = b20[0], w21s = w21[0], b21s = b21[0];
    #pragma unroll
    for (int nt = 0; nt < 4; nt++){
      float dx2 = w21s*lrelu(psB[nt] + b20s) + b21s;
      out[(size_t)b*L_ + l0 + wid*64 + nt*16 + col] = psA[nt] + 0.1f*dx2;
    }
  }
}

extern "C" void kernel_launch(void* const* d_in, const int* in_sizes, int n_in,
                              void* d_out, int out_size, void* d_ws, size_t ws_size,
                              hipStream_t stream) {
  (void)in_sizes; (void)n_in; (void)out_size; (void)ws_size;
  const float* codes   = (const float*)d_in[0];
  const int*   y       = (const int*)  d_in[1];
  const float* fc_w    = (const float*)d_in[2];
  const float* fc_b    = (const float*)d_in[3];
  const float* in_w0   = (const float*)d_in[4];
  const float* in_b0   = (const float*)d_in[5];
  const float* in_w1   = (const float*)d_in[6];
  const float* in_b1   = (const float*)d_in[7];
  const float* in_wsp  = (const float*)d_in[8];
  const float* leak    = (const float*)d_in[9];
  const float* hyper_w = (const float*)d_in[10];
  const float* hyper_b = (const float*)d_in[11];
  const float* out_w0  = (const float*)d_in[12];
  const float* out_b0  = (const float*)d_in[13];
  const float* out_w1  = (const float*)d_in[14];
  const float* out_b1  = (const float*)d_in[15];
  const float* l1_w0   = (const float*)d_in[16];
  const float* l1_b0   = (const float*)d_in[17];
  const float* l1_w1   = (const float*)d_in[18];
  const float* l1_b1   = (const float*)d_in[19];
  const float* l2_w0   = (const float*)d_in[20];
  const float* l2_b0   = (const float*)d_in[21];
  const float* l2_w1   = (const float*)d_in[22];
  const float* l2_b1   = (const float*)d_in[23];
  const float* l2_ws   = (const float*)d_in[24];
  float* out = (float*)d_out;

  char* ws = (char*)d_ws;
  unsigned short* p_bf = (unsigned short*)(ws);              // 256*37056*2 = 18,972,672
  unsigned short* ybf  = (unsigned short*)(ws + 18972672);   // 131,072
  float* x             = (float*)(ws + 19103744);            // 33,554,432
  unsigned short* t1bf = (unsigned short*)(ws + 52658176);   // 16,777,216

  k_yemb<<<B_, 256, 0, stream>>>(fc_w, fc_b, y, ybf, out);
  k_hyper<<<PT_/64, 256, 0, stream>>>(hyper_w, hyper_b, ybf, p_bf);
  k_conv_in1<<<dim3(B_, 4), 256, 0, stream>>>(codes, in_w0, in_b0, t1bf);
  k_conv_in2<<<dim3(B_, 4), 256, 0, stream>>>(codes, in_wsp, in_w1, in_b1, t1bf, x);
  k_loop<<<B_, 512, 0, stream>>>(x, p_bf, leak);
  k_conv_out1<<<dim3(B_, 4), 256, 0, stream>>>(x, out_w0, out_b0, t1bf);
  k_conv_out2<<<dim3(B_, 2), 256, 0, stream>>>(x, t1bf, out_w1, out_b1);
  k_loss<<<dim3(B_, 2), 256, 0, stream>>>(x, codes, out);
  k_lat<<<dim3(B_, 2), 256, 0, stream>>>(x, l1_w0, l1_b0, l1_w1, l1_b1,
                                         l2_w0, l2_b0, l2_w1, l2_b1, l2_ws, out);
}

// Round 11
// 814.164 us; speedup vs baseline: 1.3817x; 1.0277x over previous
//
#include <hip/hip_runtime.h>

#define B_ 256
#define C_ 64
#define L_ 512
#define CIN_ 82
#define NFREQ_ 9
#define EMB_ 256
#define NLAB_ 10
#define PT_ 37056
#define OFF_BH 16384
#define OFF_WL 16448
#define OFF_BL 20544
#define OFF_WS 20608
#define OFF_BS 36992
#define PI_F 3.14159265358979323846f

typedef short bh8 __attribute__((ext_vector_type(8)));   // 8 bf16 (raw bits)
typedef float f32x4 __attribute__((ext_vector_type(4)));

__device__ inline float lrelu(float v){ return v > 0.f ? v : 0.2f*v; }

__device__ inline unsigned short f2bf(float f){
  unsigned u = __float_as_uint(f);
  u += 0x7FFFu + ((u >> 16) & 1u);      // RNE
  return (unsigned short)(u >> 16);
}
__device__ inline float bf2f(unsigned short u){
  return __uint_as_float((unsigned)u << 16);
}
__device__ inline unsigned pk2(float a, float b){
  return (unsigned)f2bf(a) | ((unsigned)f2bf(b) << 16);
}
__device__ inline bh8 cvt8(float4 a, float4 b){
  bh8 r;
  r[0]=(short)f2bf(a.x); r[1]=(short)f2bf(a.y); r[2]=(short)f2bf(a.z); r[3]=(short)f2bf(a.w);
  r[4]=(short)f2bf(b.x); r[5]=(short)f2bf(b.y); r[6]=(short)f2bf(b.z); r[7]=(short)f2bf(b.w);
  return r;
}
__device__ inline uint4 pk8(const float* v){
  uint4 o = { pk2(v[0],v[1]), pk2(v[2],v[3]), pk2(v[4],v[5]), pk2(v[6],v[7]) };
  return o;
}
// in-wave lane fetch via LDS-pipe permute (addr = src_lane*4)
__device__ inline float shf(float v, int a){
  return __uint_as_float((unsigned)__builtin_amdgcn_ds_bpermute(a, (int)__float_as_uint(v)));
}
// non-temporal f32x4 load/store (streaming x: don't evict p from L2).
// NOTE: builtin requires a native vector type (ext_vector_type), not HIP float4.
__device__ inline f32x4 ntl4(const float* p){
  return __builtin_nontemporal_load((const f32x4*)p);
}
__device__ inline void nts4(float* p, f32x4 v){
  __builtin_nontemporal_store(v, (f32x4*)p);
}

// ---------------- yemb: normalize(fc_w[:,y]+fc_b) -> bf16 [b][e]; zero loss slot
__global__ __launch_bounds__(256) void k_yemb(const float* __restrict__ fc_w,
    const float* __restrict__ fc_b, const int* __restrict__ y,
    unsigned short* __restrict__ ybf, float* __restrict__ out){
  int b = blockIdx.x, e = threadIdx.x;
  int lab = y[b];
  float v = fc_w[e*NLAB_ + lab] + fc_b[e];
  __shared__ float red[256];
  red[e] = v*v; __syncthreads();
  for (int s = 128; s; s >>= 1){ if (e < s) red[e] += red[e+s]; __syncthreads(); }
  float nrm = fmaxf(sqrtf(red[0]), 1e-12f);
  ybf[(size_t)b*EMB_ + e] = f2bf(v / nrm);
  if (b == 0 && e == 0) out[B_*L_] = 0.f;
}

// ---------------- hyper (MFMA): p_bf[b][j] = bf16(yemb[b][:] . hw[j][:] + hb[j])
__global__ __launch_bounds__(256) void k_hyper(const float* __restrict__ hw,
    const float* __restrict__ hb, const unsigned short* __restrict__ ybf,
    unsigned short* __restrict__ p_bf){
  int tid = threadIdx.x;
  int wid = tid >> 6, lane = tid & 63, col = lane & 15, quad = lane >> 4;
  int j = blockIdx.x*64 + wid*16 + col;
  f32x4 acc[16];
  f32x4 z4 = {0.f,0.f,0.f,0.f};
  #pragma unroll
  for (int i = 0; i < 16; i++) acc[i] = z4;
  for (int k0 = 0; k0 < 256; k0 += 32){
    const float* hp = hw + (size_t)j*EMB_ + k0 + quad*8;
    bh8 bf = cvt8(*(const float4*)hp, *(const float4*)(hp+4));
    #pragma unroll
    for (int mt = 0; mt < 16; mt++){
      bh8 af = *(const bh8*)&ybf[(size_t)(mt*16 + col)*EMB_ + k0 + quad*8];
      acc[mt] = __builtin_amdgcn_mfma_f32_16x16x32_bf16(af, bf, acc[mt], 0, 0, 0);
    }
  }
  float hbv = hb[j];
  #pragma unroll
  for (int mt = 0; mt < 16; mt++){
    int b0 = mt*16 + quad*4;
    #pragma unroll
    for (int r = 0; r < 4; r++)
      p_bf[(size_t)(b0 + r)*PT_ + j] = f2bf(acc[mt][r] + hbv);
  }
}

// positional encoding value (raw)
__device__ inline float pe_raw(int fi, int l){
  if (fi < NFREQ_) return __sinf(PI_F / (float)(1 << fi) * (float)l);
  return __cosf(PI_F / (float)(1 << (fi - NFREQ_)) * (float)l);
}

// ---------------- conv_in1 (MFMA): t1bf[b][l][m] = bf16(lrelu(conv3(leaky(xcat), in_w0)+in_b0))
__global__ __launch_bounds__(256) void k_conv_in1(const float* __restrict__ codes,
    const float* __restrict__ w0, const float* __restrict__ b0,
    unsigned short* __restrict__ t1bf){
  int b = blockIdx.x, l0 = blockIdx.y*128, tid = threadIdx.x;
  int wid = tid>>6, lane = tid&63, col = lane&15, quad = lane>>4;
  __shared__ __attribute__((aligned(16))) unsigned short xT[136][96];
  __shared__ __attribute__((aligned(16))) unsigned short wA[3][64][96];
  for (int i = tid; i < 64*96; i += 256){
    int m = i / 96, cin = i % 96;
    if (cin < CIN_){
      const float* s = w0 + (size_t)m*(CIN_*3) + cin*3;
      wA[0][m][cin] = f2bf(s[0]); wA[1][m][cin] = f2bf(s[1]); wA[2][m][cin] = f2bf(s[2]);
    } else { wA[0][m][cin] = 0; wA[1][m][cin] = 0; wA[2][m][cin] = 0; }
  }
  const float* cb = codes + (size_t)b*C_*L_;
  for (int i = tid; i < 96*34; i += 256){
    int c = i / 34, g = i % 34;
    int lg = l0 - 4 + 4*g;
    #pragma unroll
    for (int r2 = 0; r2 < 4; r2++){
      int l = lg + r2;
      float xv = 0.f;
      if (l >= 0 && l < L_){
        if (c < C_) xv = cb[(size_t)c*L_ + l];
        else if (c < CIN_) xv = pe_raw(c - C_, l);
      }
      xT[4*g + r2][c] = f2bf(lrelu(xv));
    }
  }
  __syncthreads();
  f32x4 z4 = {0.f,0.f,0.f,0.f};
  f32x4 acc[8];
  #pragma unroll
  for (int i = 0; i < 8; i++) acc[i] = z4;
  #pragma unroll
  for (int t = 0; t < 3; t++){
    #pragma unroll
    for (int k0 = 0; k0 < 96; k0 += 32){
      bh8 bfr[2];
      #pragma unroll
      for (int nt = 0; nt < 2; nt++)
        bfr[nt] = *(const bh8*)&xT[wid*32 + nt*16 + col + t + 3][k0 + quad*8];
      #pragma unroll
      for (int mt = 0; mt < 4; mt++){
        bh8 af = *(const bh8*)&wA[t][mt*16 + col][k0 + quad*8];
        #pragma unroll
        for (int nt = 0; nt < 2; nt++)
          acc[mt*2+nt] = __builtin_amdgcn_mfma_f32_16x16x32_bf16(af, bfr[nt], acc[mt*2+nt], 0,0,0);
      }
    }
  }
  #pragma unroll
  for (int mt = 0; mt < 4; mt++){
    int f0 = mt*16 + quad*4;
    float q0 = b0[f0], q1 = b0[f0+1], q2 = b0[f0+2], q3 = b0[f0+3];
    #pragma unroll
    for (int nt = 0; nt < 2; nt++){
      int l = l0 + wid*32 + nt*16 + col;
      f32x4 a = acc[mt*2+nt];
      uint2 o = { pk2(lrelu(a[0]+q0), lrelu(a[1]+q1)),
                  pk2(lrelu(a[2]+q2), lrelu(a[3]+q3)) };
      *(uint2*)&t1bf[((size_t)b*L_ + l)*64 + f0] = o;
    }
  }
}

// ---------------- conv_in2 (MFMA): x = conv1x1(xcat, in_ws) + 0.1*(conv3(leaky(t1), in_w1)+in_b1)
__global__ __launch_bounds__(256) void k_conv_in2(const float* __restrict__ codes,
    const float* __restrict__ wsp, const float* __restrict__ w1, const float* __restrict__ b1,
    const unsigned short* __restrict__ t1bf, float* __restrict__ x){
  int b = blockIdx.x, l0 = blockIdx.y*128, tid = threadIdx.x;
  int wid = tid>>6, lane = tid&63, col = lane&15, quad = lane>>4;
  __shared__ __attribute__((aligned(16))) unsigned short xT[128][96];
  __shared__ __attribute__((aligned(16))) unsigned short wsA[64][96];
  __shared__ __attribute__((aligned(16))) unsigned short w1A[3][64][72];
  for (int i = tid; i < 64*96; i += 256){
    int m = i / 96, cin = i % 96;
    wsA[m][cin] = (cin < CIN_) ? f2bf(wsp[(size_t)m*CIN_ + cin]) : (unsigned short)0;
  }
  for (int i = tid; i < 64*64; i += 256){
    int m = i >> 6, cin = i & 63;
    const float* s = w1 + (size_t)m*192 + cin*3;
    w1A[0][m][cin] = f2bf(s[0]); w1A[1][m][cin] = f2bf(s[1]); w1A[2][m][cin] = f2bf(s[2]);
  }
  const float* cb = codes + (size_t)b*C_*L_;
  for (int i = tid; i < 96*32; i += 256){
    int c = i / 32, g = i % 32;
    int lg = l0 + 4*g;
    #pragma unroll
    for (int r2 = 0; r2 < 4; r2++){
      int l = lg + r2;
      float xv;
      if (c < C_) xv = cb[(size_t)c*L_ + l];
      else if (c < CIN_) xv = pe_raw(c - C_, l);
      else xv = 0.f;
      xT[4*g + r2][c] = f2bf(xv);
    }
  }
  __syncthreads();
  f32x4 z4 = {0.f,0.f,0.f,0.f};
  f32x4 accS[8], accD[8];
  #pragma unroll
  for (int i = 0; i < 8; i++){ accS[i] = z4; accD[i] = z4; }
  #pragma unroll
  for (int k0 = 0; k0 < 96; k0 += 32){
    bh8 bfr[2];
    #pragma unroll
    for (int nt = 0; nt < 2; nt++)
      bfr[nt] = *(const bh8*)&xT[wid*32 + nt*16 + col][k0 + quad*8];
    #pragma unroll
    for (int mt = 0; mt < 4; mt++){
      bh8 af = *(const bh8*)&wsA[mt*16 + col][k0 + quad*8];
      #pragma unroll
      for (int nt = 0; nt < 2; nt++)
        accS[mt*2+nt] = __builtin_amdgcn_mfma_f32_16x16x32_bf16(af, bfr[nt], accS[mt*2+nt], 0,0,0);
    }
  }
  bh8 zz8 = {0,0,0,0,0,0,0,0};
  #pragma unroll
  for (int t = 0; t < 3; t++){
    #pragma unroll
    for (int k0 = 0; k0 < 64; k0 += 32){
      bh8 bfr[2];
      #pragma unroll
      for (int nt = 0; nt < 2; nt++){
        int l = l0 + wid*32 + nt*16 + col + t - 1;
        bfr[nt] = (l >= 0 && l < L_)
          ? *(const bh8*)&t1bf[((size_t)b*L_ + l)*64 + k0 + quad*8] : zz8;
      }
      #pragma unroll
      for (int mt = 0; mt < 4; mt++){
        bh8 af = *(const bh8*)&w1A[t][mt*16 + col][k0 + quad*8];
        #pragma unroll
        for (int nt = 0; nt < 2; nt++)
          accD[mt*2+nt] = __builtin_amdgcn_mfma_f32_16x16x32_bf16(af, bfr[nt], accD[mt*2+nt], 0,0,0);
      }
    }
  }
  #pragma unroll
  for (int mt = 0; mt < 4; mt++){
    int f0 = mt*16 + quad*4;
    float q0 = b1[f0], q1 = b1[f0+1], q2 = b1[f0+2], q3 = b1[f0+3];
    #pragma unroll
    for (int nt = 0; nt < 2; nt++){
      int l = l0 + wid*32 + nt*16 + col;
      f32x4 s = accS[mt*2+nt], d = accD[mt*2+nt];
      size_t base = ((size_t)b*C_ + f0)*L_ + l;
      x[base]        = s[0] + 0.1f*(d[0] + q0);
      x[base + L_]   = s[1] + 0.1f*(d[1] + q1);
      x[base + 2*L_] = s[2] + 0.1f*(d[2] + q2);
      x[base + 3*L_] = s[3] + 0.1f*(d[3] + q3);
    }
  }
}

// ---------------- fused 8-iteration hypernet loop, deferred-update + nt-x + hoisted-p.
// (1) x loads/stores in the loop are NON-TEMPORAL so the 33.5MB/iter x stream
// stops evicting p (74KB/block, 2.4MB/XCD) from L2 -> p loads become ~200cy L2
// hits instead of ~900cy HBM misses; (2) the GEMM's p loads are hoisted in
// groups of 4 (16 transient VGPRs, fits 256/wave) -> 2 latency exposures/chunk.
#define CGS 520              // u16 stride between channels within a group
#define GGS 4168             // u16 stride between sobel-groups (8*520+8)
#define TBUF_ 16672          // one chunk buffer: 4*GGS u16
#define UST 520              // U row stride in u16 (512 + 8 pad)
#define SOBEL(CN, TP) { \
      float r[8] = {nv0[0],nv0[1],nv0[2],nv0[3],nv1[0],nv1[1],nv1[2],nv1[3]}; \
      if (aplu){ \
        const uint4 uv = *(const uint4*)&Ub[(size_t)((CN)*8 + wid)*UST + lane*8]; \
        r[0] += bf2f((unsigned short)(uv.x & 0xffffu)); r[1] += bf2f((unsigned short)(uv.x >> 16)); \
        r[2] += bf2f((unsigned short)(uv.y & 0xffffu)); r[3] += bf2f((unsigned short)(uv.y >> 16)); \
        r[4] += bf2f((unsigned short)(uv.z & 0xffffu)); r[5] += bf2f((unsigned short)(uv.z >> 16)); \
        r[6] += bf2f((unsigned short)(uv.w & 0xffffu)); r[7] += bf2f((unsigned short)(uv.w >> 16)); \
        float* xw = xb + (size_t)((CN)*8 + wid)*L_ + lane*8; \
        f32x4 w0 = {r[0],r[1],r[2],r[3]}, w1 = {r[4],r[5],r[6],r[7]}; \
        nts4(xw, w0); nts4(xw + 4, w1); \
      } \
      if ((CN) < 7){ \
        const float* xp = xb + (size_t)(((CN)+1)*8 + wid)*L_ + lane*8; \
        nv0 = ntl4(xp); nv1 = ntl4(xp + 4); \
      } \
      float s1 = 0.f, s2 = 0.f; \
      _Pragma("unroll") \
      for (int i = 0; i < 8; i++){ s1 += r[i]; s2 += r[i]*r[i]; } \
      _Pragma("unroll") \
      for (int m = 32; m; m >>= 1){ s1 += __shfl_xor(s1, m); s2 += __shfl_xor(s2, m); } \
      const float mean = s1 * (1.f/512.f); \
      const float rstd = rsqrtf(s2*(1.f/512.f) - mean*mean + 1e-5f); \
      float xn[8]; \
      _Pragma("unroll") \
      for (int i = 0; i < 8; i++) xn[i] = (r[i]-mean)*rstd; \
      *(uint4*)&(TP)[wid*CGS + lane*8] = pk8(xn); \
      float A[8], Bv[8]; \
      A[0] = 2.f*xn[0]+xn[1]; Bv[0] = xn[1]; \
      _Pragma("unroll") \
      for (int i = 1; i < 7; i++){ A[i] = xn[i-1]+2.f*xn[i]+xn[i+1]; Bv[i] = xn[i+1]-xn[i-1]; } \
      A[7] = xn[6]+2.f*xn[7]; Bv[7] = -xn[6]; \
      float Cv[8], Dv[8], Ev[8]; \
      _Pragma("unroll") \
      for (int i = 0; i < 8; i++){ \
        float am = shf(A[i], lmA)*wm, ap = shf(A[i], lpA)*wp; \
        Cv[i] = am + 2.f*A[i] + ap; \
        Dv[i] = ap - am; \
        float bm = shf(Bv[i], lmA)*wm, bp = shf(Bv[i], lpA)*wp; \
        Ev[i] = bm + 2.f*Bv[i] + bp; \
      } \
      float g0[8], g1[8], g2[8]; \
      _Pragma("unroll") \
      for (int i = 0; i < 8; i++){ \
        g0[i] = __sinf(shf(Cv[i], zpA)*qp - shf(Cv[i], zmA)*qm); \
        g1[i] = __sinf(shf(Dv[i], zmA)*qm + 2.f*Dv[i] + shf(Dv[i], zpA)*qp); \
        g2[i] = __sinf(shf(Ev[i], zmA)*qm + 2.f*Ev[i] + shf(Ev[i], zpA)*qp); \
      } \
      *(uint4*)&(TP)[GGS   + wid*CGS + lane*8] = pk8(g0); \
      *(uint4*)&(TP)[2*GGS + wid*CGS + lane*8] = pk8(g1); \
      *(uint4*)&(TP)[3*GGS + wid*CGS + lane*8] = pk8(g2); \
    }

__global__ __launch_bounds__(512, 1) void k_loop(float* __restrict__ x,
    const unsigned short* __restrict__ p_bf, const float* __restrict__ leak){
  const int b = blockIdx.x, tid = threadIdx.x;
  const int wid = tid >> 6, lane = tid & 63, col = lane & 15, quad = lane >> 4;
  const int yy = lane & 7, zz = lane >> 3;
  const unsigned short* pb = p_bf + (size_t)b*PT_;
  float* xb = x + (size_t)b*C_*L_;

  // [0, 36864) u16: T double-buffer (2 x TBUF_) / h_t[512][72] alias
  // [36864, 36864+64*UST) u16: U deferred-update buffer (bf16 [64][UST])
  __shared__ __attribute__((aligned(16))) unsigned short SMEM[36864 + 64*UST]; // 140,288 B
  unsigned short* Tb = SMEM;
  unsigned short (*h_t)[72] = (unsigned short (*)[72])SMEM;
  unsigned short* Ub = SMEM + 36864;

  const int lmA = ((yy > 0) ? lane-1 : lane)*4;  const float wm = (yy > 0) ? 1.f : 0.f;
  const int lpA = ((yy < 7) ? lane+1 : lane)*4;  const float wp = (yy < 7) ? 1.f : 0.f;
  const int zmA = ((zz > 0) ? lane-8 : lane)*4;  const float qm = (zz > 0) ? 1.f : 0.f;
  const int zpA = ((zz < 7) ? lane+8 : lane)*4;  const float qp = (zz < 7) ? 1.f : 0.f;

  const float lk = fminf(fmaxf(leak[0], 0.001f), 1000.f);
  const f32x4 z4 = {0.f,0.f,0.f,0.f};

  for (int it = 0; it < 8; ++it){
    const bool aplu = (it > 0);
    f32x4 acc1[32];                      // [mt 0..3]=wh-part, [mt 4..7]=ws-part
    #pragma unroll
    for (int i = 0; i < 32; i++) acc1[i] = z4;

    // chunk 0 x row + sobel(0) prologue
    f32x4 nv0, nv1;
    { const float* xp = xb + (size_t)wid*L_ + lane*8;
      nv0 = ntl4(xp); nv1 = ntl4(xp + 4); }
    SOBEL(0, Tb)
    __syncthreads();

    #pragma unroll 2
    for (int cc = 0; cc < 8; ++cc){
      unsigned short* Tc = Tb + (cc&1)*TBUF_;
      unsigned short* Tn = Tb + ((cc+1)&1)*TBUF_;
      if (cc < 7) SOBEL(cc+1, Tn)
      // ---- GEMM(cc): K=32 slice, phys k = quad*64 + cc*8 + j
      { bh8 bfr[4];
        #pragma unroll
        for (int nt = 0; nt < 4; nt++){
          const int n = wid*64 + nt*16 + col;
          bh8 fv;
          #pragma unroll
          for (int j = 0; j < 8; j++) fv[j] = (short)Tc[quad*GGS + j*CGS + n];
          bfr[nt] = fv;
        }
        const int kof = quad*64 + cc*8;
        bh8 ah[4];
        #pragma unroll
        for (int mt = 0; mt < 4; mt++)
          ah[mt] = *(const bh8*)&pb[(size_t)(mt*16+col)*256 + kof];
        #pragma unroll
        for (int mt = 0; mt < 4; mt++){
          #pragma unroll
          for (int nt = 0; nt < 4; nt++)
            acc1[mt*4+nt] = __builtin_amdgcn_mfma_f32_16x16x32_bf16(ah[mt], bfr[nt], acc1[mt*4+nt], 0,0,0);
        }
        #pragma unroll
        for (int mt = 0; mt < 4; mt++)
          ah[mt] = *(const bh8*)&pb[OFF_WS + (size_t)(mt*16+col)*256 + kof];
        #pragma unroll
        for (int mt = 0; mt < 4; mt++){
          #pragma unroll
          for (int nt = 0; nt < 4; nt++)
            acc1[(mt+4)*4+nt] = __builtin_amdgcn_mfma_f32_16x16x32_bf16(ah[mt], bfr[nt], acc1[(mt+4)*4+nt], 0,0,0);
        }
      }
      __syncthreads();
    }

    // ---- h epilogue -> h_t (writer and reader rows within the same wave)
    #pragma unroll
    for (int mt = 0; mt < 4; mt++){
      const int f0 = mt*16 + quad*4;
      const float bh0 = bf2f(pb[OFF_BH+f0]),   bh1 = bf2f(pb[OFF_BH+f0+1]);
      const float bh2 = bf2f(pb[OFF_BH+f0+2]), bh3 = bf2f(pb[OFF_BH+f0+3]);
      #pragma unroll
      for (int nt = 0; nt < 4; nt++){
        const int n = wid*64 + nt*16 + col;
        f32x4 a = acc1[mt*4+nt];
        uint2 o = { pk2(lrelu(a[0]+bh0), lrelu(a[1]+bh1)),
                    pk2(lrelu(a[2]+bh2), lrelu(a[3]+bh3)) };
        *(uint2*)&h_t[n][f0] = o;
      }
    }
    // ---- GEMM2: wl @ h (intra-wave LDS, DS pipe in-order -> no barrier)
    f32x4 acc2[16];
    #pragma unroll
    for (int i = 0; i < 16; i++) acc2[i] = z4;
    #pragma unroll
    for (int k0 = 0; k0 < 64; k0 += 32){
      bh8 hb[4];
      #pragma unroll
      for (int nt = 0; nt < 4; nt++)
        hb[nt] = *(const bh8*)&h_t[wid*64 + nt*16 + col][k0 + quad*8];
      #pragma unroll
      for (int mt = 0; mt < 4; mt++){
        bh8 al = *(const bh8*)&pb[OFF_WL + (size_t)(mt*16 + col)*64 + k0 + quad*8];
        #pragma unroll
        for (int nt = 0; nt < 4; nt++)
          acc2[mt*4+nt] = __builtin_amdgcn_mfma_f32_16x16x32_bf16(al, hb[nt], acc2[mt*4+nt], 0,0,0);
      }
    }

    if (it < 7){
      // ---- deferred update: U[c][s] = bf16(lk*(xs + bs + 0.1*(dx + bl))) in LDS
      #pragma unroll
      for (int mt = 0; mt < 4; mt++){
        const int f0 = mt*16 + quad*4;
        const float bs0 = bf2f(pb[OFF_BS+f0]),   bs1 = bf2f(pb[OFF_BS+f0+1]);
        const float bs2 = bf2f(pb[OFF_BS+f0+2]), bs3 = bf2f(pb[OFF_BS+f0+3]);
        const float bl0 = bf2f(pb[OFF_BL+f0]),   bl1 = bf2f(pb[OFF_BL+f0+1]);
        const float bl2 = bf2f(pb[OFF_BL+f0+2]), bl3 = bf2f(pb[OFF_BL+f0+3]);
        #pragma unroll
        for (int nt = 0; nt < 4; nt++){
          const int n = wid*64 + nt*16 + col;
          f32x4 xs = acc1[(mt+4)*4+nt], dx = acc2[mt*4+nt];
          Ub[(size_t)(f0+0)*UST + n] = f2bf(lk*(xs[0] + bs0 + 0.1f*(dx[0] + bl0)));
          Ub[(size_t)(f0+1)*UST + n] = f2bf(lk*(xs[1] + bs1 + 0.1f*(dx[1] + bl1)));
          Ub[(size_t)(f0+2)*UST + n] = f2bf(lk*(xs[2] + bs2 + 0.1f*(dx[2] + bl2)));
          Ub[(size_t)(f0+3)*UST + n] = f2bf(lk*(xs[3] + bs3 + 0.1f*(dx[3] + bl3)));
        }
      }
    } else {
      // ---- final iteration: apply update via global RMW (x was last written by
      // phase A cross-wave -> fence + barrier before reading)
      __threadfence_block();
      __syncthreads();
      #pragma unroll
      for (int mt = 0; mt < 4; mt++){
        const int f0 = mt*16 + quad*4;
        const float bs0 = bf2f(pb[OFF_BS+f0]),   bs1 = bf2f(pb[OFF_BS+f0+1]);
        const float bs2 = bf2f(pb[OFF_BS+f0+2]), bs3 = bf2f(pb[OFF_BS+f0+3]);
        const float bl0 = bf2f(pb[OFF_BL+f0]),   bl1 = bf2f(pb[OFF_BL+f0+1]);
        const float bl2 = bf2f(pb[OFF_BL+f0+2]), bl3 = bf2f(pb[OFF_BL+f0+3]);
        #pragma unroll
        for (int nt = 0; nt < 4; nt++){
          const int n = wid*64 + nt*16 + col;
          f32x4 xs = acc1[(mt+4)*4+nt], dx = acc2[mt*4+nt];
          size_t xi = (size_t)f0*L_ + n;
          xb[xi]        += lk*(xs[0] + bs0 + 0.1f*(dx[0] + bl0));
          xb[xi + L_]   += lk*(xs[1] + bs1 + 0.1f*(dx[1] + bl1));
          xb[xi + 2*L_] += lk*(xs[2] + bs2 + 0.1f*(dx[2] + bl2));
          xb[xi + 3*L_] += lk*(xs[3] + bs3 + 0.1f*(dx[3] + bl3));
        }
      }
    }
    __threadfence_block();
    __syncthreads();   // U visible to next phase A + T/h_t alias boundary
  }
}

// ---------------- conv_out1 (MFMA): t1bf = bf16(lrelu(conv3(leaky(x), out_w0)+out_b0))
__global__ __launch_bounds__(256) void k_conv_out1(const float* __restrict__ x,
    const float* __restrict__ w, const float* __restrict__ bias,
    unsigned short* __restrict__ t1bf){
  int b = blockIdx.x, l0 = blockIdx.y*128, tid = threadIdx.x;
  int wid = tid>>6, lane = tid&63, col = lane&15, quad = lane>>4;
  __shared__ __attribute__((aligned(16))) unsigned short xT[136][72];
  __shared__ __attribute__((aligned(16))) unsigned short wA[3][64][72];
  for (int i = tid; i < 64*64; i += 256){
    int m = i >> 6, cin = i & 63;
    const float* s = w + (size_t)m*192 + cin*3;
    wA[0][m][cin] = f2bf(s[0]); wA[1][m][cin] = f2bf(s[1]); wA[2][m][cin] = f2bf(s[2]);
  }
  const float* xb = x + (size_t)b*C_*L_;
  for (int i = tid; i < 64*34; i += 256){
    int c = i / 34, g = i % 34;
    int lg = l0 - 4 + 4*g;
    if (lg >= 0 && lg + 3 < L_){
      float4 f = *(const float4*)&xb[(size_t)c*L_ + lg];
      xT[4*g  ][c] = f2bf(lrelu(f.x));
      xT[4*g+1][c] = f2bf(lrelu(f.y));
      xT[4*g+2][c] = f2bf(lrelu(f.z));
      xT[4*g+3][c] = f2bf(lrelu(f.w));
    } else {
      #pragma unroll
      for (int r2 = 0; r2 < 4; r2++){
        int l = lg + r2;
        float v = (l >= 0 && l < L_) ? xb[(size_t)c*L_ + l] : 0.f;
        xT[4*g + r2][c] = f2bf(lrelu(v));
      }
    }
  }
  __syncthreads();
  f32x4 z4 = {0.f,0.f,0.f,0.f};
  f32x4 acc[8];
  #pragma unroll
  for (int i = 0; i < 8; i++) acc[i] = z4;
  #pragma unroll
  for (int t = 0; t < 3; t++){
    #pragma unroll
    for (int k0 = 0; k0 < 64; k0 += 32){
      bh8 bfr[2];
      #pragma unroll
      for (int nt = 0; nt < 2; nt++)
        bfr[nt] = *(const bh8*)&xT[wid*32 + nt*16 + col + t + 3][k0 + quad*8];
      #pragma unroll
      for (int mt = 0; mt < 4; mt++){
        bh8 af = *(const bh8*)&wA[t][mt*16 + col][k0 + quad*8];
        #pragma unroll
        for (int nt = 0; nt < 2; nt++)
          acc[mt*2+nt] = __builtin_amdgcn_mfma_f32_16x16x32_bf16(af, bfr[nt], acc[mt*2+nt], 0,0,0);
      }
    }
  }
  #pragma unroll
  for (int mt = 0; mt < 4; mt++){
    int f0 = mt*16 + quad*4;
    float q0 = bias[f0], q1 = bias[f0+1], q2 = bias[f0+2], q3 = bias[f0+3];
    #pragma unroll
    for (int nt = 0; nt < 2; nt++){
      int l = l0 + wid*32 + nt*16 + col;
      f32x4 a = acc[mt*2+nt];
      uint2 o = { pk2(lrelu(a[0]+q0), lrelu(a[1]+q1)),
                  pk2(lrelu(a[2]+q2), lrelu(a[3]+q3)) };
      *(uint2*)&t1bf[((size_t)b*L_ + l)*64 + f0] = o;
    }
  }
}

// ---------------- conv_out2 (MFMA): x += 0.1*(conv3(leaky(t1), out_w1)+out_b1)
__global__ __launch_bounds__(256) void k_conv_out2(float* __restrict__ x,
    const unsigned short* __restrict__ t1bf, const float* __restrict__ w,
    const float* __restrict__ bias){
  int b = blockIdx.x, l0 = blockIdx.y*256, tid = threadIdx.x;
  int wid = tid>>6, lane = tid&63, col = lane&15, quad = lane>>4;
  __shared__ __attribute__((aligned(16))) unsigned short wA[3][64][72];
  for (int i = tid; i < 64*64; i += 256){
    int m = i >> 6, cin = i & 63;
    const float* s = w + (size_t)m*192 + cin*3;
    wA[0][m][cin] = f2bf(s[0]); wA[1][m][cin] = f2bf(s[1]); wA[2][m][cin] = f2bf(s[2]);
  }
  __syncthreads();
  f32x4 z4 = {0.f,0.f,0.f,0.f};
  f32x4 acc[16];
  #pragma unroll
  for (int i = 0; i < 16; i++) acc[i] = z4;
  bh8 zz8 = {0,0,0,0,0,0,0,0};
  #pragma unroll
  for (int t = 0; t < 3; t++){
    #pragma unroll
    for (int k0 = 0; k0 < 64; k0 += 32){
      bh8 bfr[4];
      #pragma unroll
      for (int nt = 0; nt < 4; nt++){
        int l = l0 + wid*64 + nt*16 + col + t - 1;
        bfr[nt] = (l >= 0 && l < L_)
          ? *(const bh8*)&t1bf[((size_t)b*L_ + l)*64 + k0 + quad*8] : zz8;
      }
      #pragma unroll
      for (int mt = 0; mt < 4; mt++){
        bh8 af = *(const bh8*)&wA[t][mt*16 + col][k0 + quad*8];
        #pragma unroll
        for (int nt = 0; nt < 4; nt++)
          acc[mt*4+nt] = __builtin_amdgcn_mfma_f32_16x16x32_bf16(af, bfr[nt], acc[mt*4+nt], 0,0,0);
      }
    }
  }
  #pragma unroll
  for (int mt = 0; mt < 4; mt++){
    int f0 = mt*16 + quad*4;
    float q0 = bias[f0], q1 = bias[f0+1], q2 = bias[f0+2], q3 = bias[f0+3];
    #pragma unroll
    for (int nt = 0; nt < 4; nt++){
      int l = l0 + wid*64 + nt*16 + col;
      f32x4 a = acc[mt*4+nt];
      size_t base = ((size_t)b*C_ + f0)*L_ + l;
      x[base]        += 0.1f*(a[0] + q0);
      x[base + L_]   += 0.1f*(a[1] + q1);
      x[base + 2*L_] += 0.1f*(a[2] + q2);
      x[base + 3*L_] += 0.1f*(a[3] + q3);
    }
  }
}

// ---------------- loss: cross-entropy vs argmax(codes)
__global__ __launch_bounds__(256) void k_loss(const float* __restrict__ x,
    const float* __restrict__ codes, float* __restrict__ out){
  int b = blockIdx.x;
  int l = blockIdx.y*256 + threadIdx.x;
  const float* xb = x + (size_t)b*C_*L_ + l;
  const float* cb = codes + (size_t)b*C_*L_ + l;
  float m = -1e30f, cm = -1e30f;
  int ci = 0;
  for (int c = 0; c < C_; c++){
    float xv = xb[(size_t)c*L_];
    m = fmaxf(m, xv);
    float cv = cb[(size_t)c*L_];
    if (cv > cm){ cm = cv; ci = c; }
  }
  float s = 0.f, vi = 0.f;
  for (int c = 0; c < C_; c++){
    float xv = xb[(size_t)c*L_];
    s += expf(xv - m);
    if (c == ci) vi = xv;
  }
  float lp = vi - m - logf(s);
  __shared__ float red[256];
  red[threadIdx.x] = -lp; __syncthreads();
  for (int sft = 128; sft; sft >>= 1){
    if (threadIdx.x < sft) red[threadIdx.x] += red[threadIdx.x + sft];
    __syncthreads();
  }
  if (threadIdx.x == 0) atomicAdd(out + B_*L_, red[0] * (1.0f/131072.0f));
}

// ---------------- lat head (MFMA): two 64x64 GEMMs per (b, 256-col tile) + lat2 reduce
__global__ __launch_bounds__(256) void k_lat(const float* __restrict__ x,
    const float* __restrict__ w10, const float* __restrict__ b10,
    const float* __restrict__ w11, const float* __restrict__ b11,
    const float* __restrict__ w20, const float* __restrict__ b20,
    const float* __restrict__ w21, const float* __restrict__ b21,
    const float* __restrict__ ws2, float* __restrict__ out){
  int b = blockIdx.x, l0 = blockIdx.y*256;
  int tid = threadIdx.x;
  int wid = tid >> 6, lane = tid & 63, col = lane & 15, quad = lane >> 4;
  __shared__ __attribute__((aligned(16))) unsigned short wA[2][64][72];
  __shared__ __attribute__((aligned(16))) unsigned short Bt[256][72];

  for (int i = tid; i < 1024; i += 256){
    int arr = i >> 9, rem = i & 511, row = rem >> 3, seg = rem & 7;
    const float* src = (arr ? w11 : w10) + (size_t)row*C_ + seg*8;
    *(bh8*)&wA[arr][row][seg*8] = cvt8(*(const float4*)src, *(const float4*)(src+4));
  }
  for (int i = tid; i < 4096; i += 256){
    int c = i >> 6, seg = i & 63;
    float4 v = *(const float4*)&x[((size_t)b*C_ + c)*L_ + l0 + seg*4];
    Bt[seg*4+0][c] = f2bf(lrelu(v.x));
    Bt[seg*4+1][c] = f2bf(lrelu(v.y));
    Bt[seg*4+2][c] = f2bf(lrelu(v.z));
    Bt[seg*4+3][c] = f2bf(lrelu(v.w));
  }
  __syncthreads();
  f32x4 z4 = {0.f,0.f,0.f,0.f};
  f32x4 acc1[16];
  #pragma unroll
  for (int i = 0; i < 16; i++) acc1[i] = z4;
  #pragma unroll
  for (int k0 = 0; k0 < 64; k0 += 32){
    bh8 bfr[4];
    #pragma unroll
    for (int nt = 0; nt < 4; nt++)
      bfr[nt] = *(const bh8*)&Bt[wid*64 + nt*16 + col][k0 + quad*8];
    #pragma unroll
    for (int mt = 0; mt < 4; mt++){
      bh8 af = *(const bh8*)&wA[0][mt*16 + col][k0 + quad*8];
      #pragma unroll
      for (int nt = 0; nt < 4; nt++)
        acc1[mt*4+nt] = __builtin_amdgcn_mfma_f32_16x16x32_bf16(af, bfr[nt], acc1[mt*4+nt], 0, 0, 0);
    }
  }
  #pragma unroll
  for (int mt = 0; mt < 4; mt++){
    int f0 = mt*16 + quad*4;
    f32x4 bv = *(const f32x4*)&b10[f0];
    #pragma unroll
    for (int nt = 0; nt < 4; nt++){
      int n = wid*64 + nt*16 + col;
      f32x4 a = acc1[mt*4+nt];
      uint2 o = { pk2(lrelu(a[0]+bv[0]), lrelu(a[1]+bv[1])),
                  pk2(lrelu(a[2]+bv[2]), lrelu(a[3]+bv[3])) };
      *(uint2*)&Bt[n][f0] = o;
    }
  }
  f32x4 acc2[16];
  #pragma unroll
  for (int i = 0; i < 16; i++) acc2[i] = z4;
  #pragma unroll
  for (int k0 = 0; k0 < 64; k0 += 32){
    bh8 bfr[4];
    #pragma unroll
    for (int nt = 0; nt < 4; nt++)
      bfr[nt] = *(const bh8*)&Bt[wid*64 + nt*16 + col][k0 + quad*8];
    #pragma unroll
    for (int mt = 0; mt < 4; mt++){
      bh8 af = *(const bh8*)&wA[1][mt*16 + col][k0 + quad*8];
      #pragma unroll
      for (int nt = 0; nt < 4; nt++)
        acc2[mt*4+nt] = __builtin_amdgcn_mfma_f32_16x16x32_bf16(af, bfr[nt], acc2[mt*4+nt], 0, 0, 0);
    }
  }
  float psA[4] = {0.f,0.f,0.f,0.f}, psB[4] = {0.f,0.f,0.f,0.f};
  #pragma unroll
  for (int mt = 0; mt < 4; mt++){
    int f0 = mt*16 + quad*4;
    f32x4 b11v = *(const f32x4*)&b11[f0];
    f32x4 wsv  = *(const f32x4*)&ws2[f0];
    f32x4 w20v = *(const f32x4*)&w20[f0];
    #pragma unroll
    for (int nt = 0; nt < 4; nt++){
      int lg = l0 + wid*64 + nt*16 + col;
      size_t base = ((size_t)b*C_ + f0)*L_ + lg;
      f32x4 a = acc2[mt*4+nt];
      #pragma unroll
      for (int r = 0; r < 4; r++){
        float xv = x[base + (size_t)r*L_];
        float lat = xv + 0.1f*(a[r] + b11v[r]);
        psA[nt] += wsv[r]*lat;
        psB[nt] += w20v[r]*lrelu(lat);
      }
    }
  }
  #pragma unroll
  for (int nt = 0; nt < 4; nt++){
    psA[nt] += __shfl_xor(psA[nt], 16); psA[nt] += __shfl_xor(psA[nt], 32);
    psB[nt] += __shfl_xor(psB[nt], 16); psB[nt] += __shfl_xor(psB[nt], 32);
  }
  if (quad == 0){
    float b20s = b20[0], w21s = w21[0], b21s = b21[0];
    #pragma unroll
    for (int nt = 0; nt < 4; nt++){
      float dx2 = w21s*lrelu(psB[nt] + b20s) + b21s;
      out[(size_t)b*L_ + l0 + wid*64 + nt*16 + col] = psA[nt] + 0.1f*dx2;
    }
  }
}

extern "C" void kernel_launch(void* const* d_in, const int* in_sizes, int n_in,
                              void* d_out, int out_size, void* d_ws, size_t ws_size,
                              hipStream_t stream) {
  (void)in_sizes; (void)n_in; (void)out_size; (void)ws_size;
  const float* codes   = (const float*)d_in[0];
  const int*   y       = (const int*)  d_in[1];
  const float* fc_w    = (const float*)d_in[2];
  const float* fc_b    = (const float*)d_in[3];
  const float* in_w0   = (const float*)d_in[4];
  const float* in_b0   = (const float*)d_in[5];
  const float* in_w1   = (const float*)d_in[6];
  const float* in_b1   = (const float*)d_in[7];
  const float* in_wsp  = (const float*)d_in[8];
  const float* leak    = (const float*)d_in[9];
  const float* hyper_w = (const float*)d_in[10];
  const float* hyper_b = (const float*)d_in[11];
  const float* out_w0  = (const float*)d_in[12];
  const float* out_b0  = (const float*)d_in[13];
  const float* out_w1  = (const float*)d_in[14];
  const float* out_b1  = (const float*)d_in[15];
  const float* l1_w0   = (const float*)d_in[16];
  const float* l1_b0   = (const float*)d_in[17];
  const float* l1_w1   = (const float*)d_in[18];
  const float* l1_b1   = (const float*)d_in[19];
  const float* l2_w0   = (const float*)d_in[20];
  const float* l2_b0   = (const float*)d_in[21];
  const float* l2_w1   = (const float*)d_in[22];
  const float* l2_b1   = (const float*)d_in[23];
  const float* l2_ws   = (const float*)d_in[24];
  float* out = (float*)d_out;

  char* ws = (char*)d_ws;
  unsigned short* p_bf = (unsigned short*)(ws);              // 256*37056*2 = 18,972,672
  unsigned short* ybf  = (unsigned short*)(ws + 18972672);   // 131,072
  float* x             = (float*)(ws + 19103744);            // 33,554,432
  unsigned short* t1bf = (unsigned short*)(ws + 52658176);   // 16,777,216

  k_yemb<<<B_, 256, 0, stream>>>(fc_w, fc_b, y, ybf, out);
  k_hyper<<<PT_/64, 256, 0, stream>>>(hyper_w, hyper_b, ybf, p_bf);
  k_conv_in1<<<dim3(B_, 4), 256, 0, stream>>>(codes, in_w0, in_b0, t1bf);
  k_conv_in2<<<dim3(B_, 4), 256, 0, stream>>>(codes, in_wsp, in_w1, in_b1, t1bf, x);
  k_loop<<<B_, 512, 0, stream>>>(x, p_bf, leak);
  k_conv_out1<<<dim3(B_, 4), 256, 0, stream>>>(x, out_w0, out_b0, t1bf);
  k_conv_out2<<<dim3(B_, 2), 256, 0, stream>>>(x, t1bf, out_w1, out_b1);
  k_loss<<<dim3(B_, 2), 256, 0, stream>>>(x, codes, out);
  k_lat<<<dim3(B_, 2), 256, 0, stream>>>(x, l1_w0, l1_b0, l1_w1, l1_b1,
                                         l2_w0, l2_b0, l2_w1, l2_b1, l2_ws, out);
}